// Round 7
// baseline (1801.049 us; speedup 1.0000x reference)
//
#include <hip/hip_runtime.h>
#include <hip/hip_bf16.h>
#include <math.h>

#define N_NODES 100000
#define N_FEAT 500
#define N_HID 256
#define N_CLASS 40
#define BIN_CAP 448000
#define PLANE 400000  // ushorts per hg plane: 100000 rows * 4 feats

typedef float f32x4 __attribute__((ext_vector_type(4)));
typedef int i32x4 __attribute__((ext_vector_type(4)));
typedef short short8 __attribute__((ext_vector_type(8)));
typedef unsigned short u16x8 __attribute__((ext_vector_type(8)));

__device__ __forceinline__ float b2f(unsigned short u) {
  union { unsigned int i; float f; } c; c.i = ((unsigned int)u) << 16; return c.f;
}
__device__ __forceinline__ unsigned short f2bu(float x) {
  __hip_bfloat16 b = __float2bfloat16(x);
  union { __hip_bfloat16 b; unsigned short u; } c; c.b = b; return c.u;
}
__device__ __forceinline__ float decode_val(unsigned int p) {
  union { unsigned int i; float f; } c; c.i = (p & 0x7FFFu) << 17; return c.f;
}
__device__ __forceinline__ void gload_lds16(const void* gptr, void* lptr) {
  __builtin_amdgcn_global_load_lds(
      (const __attribute__((address_space(1))) unsigned int*)gptr,
      (__attribute__((address_space(3))) unsigned int*)lptr, 16, 0, 0);
}

// ---------------------------------------------------------------------------
// cast W1[500][256] f32 -> W1T_sw[256][512] bf16 (transposed, padded, swizzled)
// ---------------------------------------------------------------------------
__global__ __launch_bounds__(256) void cast_w1(
    const float* __restrict__ W1, unsigned short* __restrict__ Bsw) {
  int t = blockIdx.x * 256 + threadIdx.x;
  int col = t >> 6, ch = t & 63;
  int g = ch >> 3, c = ch & 7;
  int c_src = c ^ (col & 7);
  int k = g * 64 + c_src * 8;
  u16x8 o;
#pragma unroll
  for (int j = 0; j < 8; j++) {
    int kk = k + j;
    o[j] = (kk < N_FEAT) ? f2bu(W1[(size_t)kk * N_HID + col]) : (unsigned short)0;
  }
  *(u16x8*)(Bsw + (size_t)col * 512 + g * 64 + c * 8) = o;
}

// ---------------------------------------------------------------------------
// GEMM1 (bf16 MFMA): writes h in FEATURE-GROUPED layout hg[64][100000][4]
// ---------------------------------------------------------------------------
__global__ __launch_bounds__(512) void gemm1_mfma(
    const float* __restrict__ A, const unsigned short* __restrict__ Bsw,
    const float* __restrict__ b1, unsigned short* __restrict__ HG, int M) {
  __shared__ __align__(16) char smem[49152];
  char* sA = smem;
  char* sB = smem + 16384;
  int tid = threadIdx.x;
  int lane = tid & 63, w = tid >> 6;
  int wr = w >> 2, wc = w & 3;
  int bm = blockIdx.x * 128;

  f32x4 acc[4][4];
#pragma unroll
  for (int m = 0; m < 4; m++)
#pragma unroll
    for (int n = 0; n < 4; n++) acc[m][n] = (f32x4)0.f;

  for (int s = 0; s < 8; s++) {
    int k0 = s * 64;
#pragma unroll
    for (int i = 0; i < 4; i++) {
      int f4 = i * 512 + tid;
      int row = f4 >> 4, cidx = f4 & 15;
      int grow = bm + row;
      int k = k0 + cidx * 4;
      float4 v = make_float4(0.f, 0.f, 0.f, 0.f);
      if (grow < M && k < N_FEAT) v = *(const float4*)(A + (size_t)grow * N_FEAT + k);
      ushort4 u;
      u.x = f2bu(v.x); u.y = f2bu(v.y); u.z = f2bu(v.z); u.w = f2bu(v.w);
      int chunk = cidx >> 1, sub = cidx & 1;
      int byte = row * 128 + (((chunk ^ (row & 7))) << 4) + (sub << 3);
      *(ushort4*)(sA + byte) = u;
    }
#pragma unroll
    for (int j = 0; j < 4; j++) {
      int base = j * 8192 + w * 1024;
      int L = base + lane * 16;
      int col = L >> 7, c = (L >> 4) & 7;
      const char* g = (const char*)Bsw + (size_t)col * 1024 + s * 128 + c * 16;
      gload_lds16(g, sB + base);
    }
    __syncthreads();
#pragma unroll
    for (int kk = 0; kk < 2; kk++) {
      int cw = kk * 4 + (lane >> 4);
      short8 af[4], bg[4];
#pragma unroll
      for (int m = 0; m < 4; m++) {
        int ar = wr * 64 + m * 16 + (lane & 15);
        af[m] = *(const short8*)(sA + ar * 128 + ((cw ^ (ar & 7)) << 4));
      }
#pragma unroll
      for (int n = 0; n < 4; n++) {
        int bc = wc * 64 + n * 16 + (lane & 15);
        bg[n] = *(const short8*)(sB + bc * 128 + ((cw ^ (bc & 7)) << 4));
      }
#pragma unroll
      for (int m = 0; m < 4; m++)
#pragma unroll
        for (int n = 0; n < 4; n++)
          acc[m][n] = __builtin_amdgcn_mfma_f32_16x16x32_bf16(af[m], bg[n], acc[m][n], 0, 0, 0);
    }
    __syncthreads();
  }

  float bias[4];
#pragma unroll
  for (int n = 0; n < 4; n++) bias[n] = b1[wc * 64 + n * 16 + (lane & 15)];
#pragma unroll
  for (int m = 0; m < 4; m++) {
#pragma unroll
    for (int r = 0; r < 4; r++) {
      int row = bm + wr * 64 + m * 16 + ((lane >> 4) << 2) + r;
      if (row < M) {
#pragma unroll
        for (int n = 0; n < 4; n++) {
          int col = wc * 64 + n * 16 + (lane & 15);
          HG[(size_t)(col >> 2) * PLANE + (size_t)row * 4 + (col & 3)] =
              f2bu(acc[m][n][r] + bias[n]);
        }
      }
    }
  }
}

// ---------------------------------------------------------------------------
// CSR build: hist -> 3-phase scan -> two-pass scatter (bin by slice, then
// per-slice scatter on its own XCD). Edge record packed: row<<32 | cvp where
// cvp = col<<15 | (bf16(val)>>1).
// ---------------------------------------------------------------------------
__global__ __launch_bounds__(256) void hist_kernel(
    const int* __restrict__ er, int* __restrict__ cnt, int E) {
  int nv = E >> 2;
  int t = blockIdx.x * 256 + threadIdx.x;
  int nthr = gridDim.x * 256;
  const i32x4* er4 = (const i32x4*)er;
  for (int i = t; i < nv; i += nthr) {
    i32x4 r = __builtin_nontemporal_load(&er4[i]);
    atomicAdd(&cnt[r.x], 1);
    atomicAdd(&cnt[r.y], 1);
    atomicAdd(&cnt[r.z], 1);
    atomicAdd(&cnt[r.w], 1);
  }
  int tail = nv << 2;
  if (blockIdx.x == 0 && threadIdx.x < E - tail)
    atomicAdd(&cnt[er[tail + threadIdx.x]], 1);
}

__global__ __launch_bounds__(1024) void scan1_kernel(
    int* __restrict__ cnt, int* __restrict__ bsum, int n) {
  __shared__ int wsum[16];
  int tid = threadIdx.x, lane = tid & 63, wid = tid >> 6;
  int i = blockIdx.x * 1024 + tid;
  int v = (i < n) ? cnt[i] : 0;
  int x = v;
#pragma unroll
  for (int off = 1; off < 64; off <<= 1) {
    int t = __shfl_up(x, off);
    if (lane >= off) x += t;
  }
  if (lane == 63) wsum[wid] = x;
  __syncthreads();
  if (tid < 16) {
    int ws = wsum[tid];
#pragma unroll
    for (int off = 1; off < 16; off <<= 1) {
      int t = __shfl_up(ws, off);
      if (tid >= off) ws += t;
    }
    wsum[tid] = ws;
  }
  __syncthreads();
  int excl = (wid ? wsum[wid - 1] : 0) + x - v;
  if (i < n) cnt[i] = excl;
  if (tid == 0) bsum[blockIdx.x] = wsum[15];
}

__global__ __launch_bounds__(64) void scan2_kernel(
    int* __restrict__ bsum, int* __restrict__ row_ptr, int nb, int n) {
  int lane = threadIdx.x;
  int carry = 0;
  for (int base = 0; base < nb; base += 64) {
    int i = base + lane;
    int v = (i < nb) ? bsum[i] : 0;
    int x = v;
#pragma unroll
    for (int off = 1; off < 64; off <<= 1) {
      int t = __shfl_up(x, off);
      if (lane >= off) x += t;
    }
    if (i < nb) bsum[i] = carry + x - v;
    carry += __shfl(x, 63);
  }
  if (lane == 0) row_ptr[n] = carry;
}

__global__ __launch_bounds__(256) void scan3_kernel(
    int* __restrict__ cnt, const int* __restrict__ bsum,
    int* __restrict__ row_ptr, int n) {
  int i = blockIdx.x * 256 + threadIdx.x;
  if (i >= n) return;
  int v = cnt[i] + bsum[i >> 10];
  cnt[i] = v;
  row_ptr[i] = v;
}

// pass 1: bin edges into 8 slice buckets. Wave-chunked: each wave owns a
// contiguous 2048-edge chunk; counts per bucket via ballot (phase 1), does 8
// bucket atomics total, then writes records at ballot-ranked positions.
__global__ __launch_bounds__(256) void bin_kernel(
    const int* __restrict__ er, const int* __restrict__ ec,
    const float* __restrict__ ev, int* __restrict__ bcur,
    unsigned long long* __restrict__ buckets, int E) {
  int gw = (blockIdx.x * 256 + threadIdx.x) >> 6;
  int lane = threadIdx.x & 63;
  int nw = (gridDim.x * 256) >> 6;
  const int CH = 2048;
  int nchunks = (E + CH - 1) / CH;
  unsigned long long below = (1ULL << lane) - 1ULL;
  for (int ch = gw; ch < nchunks; ch += nw) {
    int base = ch * CH;
    int c0 = 0, c1 = 0, c2 = 0, c3 = 0, c4 = 0, c5 = 0, c6 = 0, c7 = 0;
    for (int i = 0; i < CH; i += 64) {
      int e = base + i + lane;
      int b = (e < E) ? ((er[e] >> 9) & 7) : -1;
      c0 += __popcll(__ballot(b == 0));
      c1 += __popcll(__ballot(b == 1));
      c2 += __popcll(__ballot(b == 2));
      c3 += __popcll(__ballot(b == 3));
      c4 += __popcll(__ballot(b == 4));
      c5 += __popcll(__ballot(b == 5));
      c6 += __popcll(__ballot(b == 6));
      c7 += __popcll(__ballot(b == 7));
    }
    int mycnt = 0;
    if (lane == 0) mycnt = c0;
    if (lane == 1) mycnt = c1;
    if (lane == 2) mycnt = c2;
    if (lane == 3) mycnt = c3;
    if (lane == 4) mycnt = c4;
    if (lane == 5) mycnt = c5;
    if (lane == 6) mycnt = c6;
    if (lane == 7) mycnt = c7;
    int mybase = 0;
    if (lane < 8) mybase = atomicAdd(&bcur[lane], mycnt);
    int o0 = __shfl(mybase, 0), o1 = __shfl(mybase, 1);
    int o2 = __shfl(mybase, 2), o3 = __shfl(mybase, 3);
    int o4 = __shfl(mybase, 4), o5 = __shfl(mybase, 5);
    int o6 = __shfl(mybase, 6), o7 = __shfl(mybase, 7);
    for (int i = 0; i < CH; i += 64) {
      int e = base + i + lane;
      int b = -1, rr = 0, cc = 0;
      float vv = 0.f;
      if (e < E) { rr = er[e]; cc = ec[e]; vv = ev[e]; b = (rr >> 9) & 7; }
      unsigned long long m0 = __ballot(b == 0), m1 = __ballot(b == 1);
      unsigned long long m2 = __ballot(b == 2), m3 = __ballot(b == 3);
      unsigned long long m4 = __ballot(b == 4), m5 = __ballot(b == 5);
      unsigned long long m6 = __ballot(b == 6), m7 = __ballot(b == 7);
      int pos = -1;
      if (b == 0) pos = o0 + __popcll(m0 & below);
      if (b == 1) pos = o1 + __popcll(m1 & below);
      if (b == 2) pos = o2 + __popcll(m2 & below);
      if (b == 3) pos = o3 + __popcll(m3 & below);
      if (b == 4) pos = o4 + __popcll(m4 & below);
      if (b == 5) pos = o5 + __popcll(m5 & below);
      if (b == 6) pos = o6 + __popcll(m6 & below);
      if (b == 7) pos = o7 + __popcll(m7 & below);
      o0 += __popcll(m0); o1 += __popcll(m1);
      o2 += __popcll(m2); o3 += __popcll(m3);
      o4 += __popcll(m4); o5 += __popcll(m5);
      o6 += __popcll(m6); o7 += __popcll(m7);
      if (e < E) {
        unsigned int cvpv = ((unsigned int)cc << 15) | ((unsigned int)f2bu(vv) >> 1);
        buckets[(size_t)b * BIN_CAP + pos] =
            ((unsigned long long)(unsigned int)rr << 32) | cvpv;
      }
    }
  }
}

// pass 2: per-slice scatter. Block b handles slice b&7 (its XCD): cursor
// atomics + cvp writes for that slice stay in one L2.
__global__ __launch_bounds__(256) void scatter2_kernel(
    const unsigned long long* __restrict__ buckets, const int* __restrict__ bcur,
    int* __restrict__ cursor, unsigned int* __restrict__ cvp) {
  int s = blockIdx.x & 7;
  int g = blockIdx.x >> 3, ngrp = gridDim.x >> 3;
  int n = bcur[s];
  const unsigned long long* B = buckets + (size_t)s * BIN_CAP;
  for (int i = g * 256 + threadIdx.x; i < n; i += ngrp * 256) {
    unsigned long long rec = B[i];
    int row = (int)(rec >> 32);
    int pos = atomicAdd(&cursor[row], 1);
    cvp[pos] = (unsigned int)rec;
  }
}

// ---------------------------------------------------------------------------
// SPMM1 feature-sliced: thread = row, 16 feats (4 planes of hg). XCD bid&7
// owns planes [s8*8, s8*8+8); dispatch-order phase picks which 4 (3.2 MB,
// L2-resident). Fused ReLU; writes hpost row-major.
// ---------------------------------------------------------------------------
__global__ __launch_bounds__(256) void spmm_fs(
    const int* __restrict__ row_ptr, const unsigned int* __restrict__ cvp,
    const unsigned short* __restrict__ HG, unsigned short* __restrict__ Y, int M) {
  int half = gridDim.x >> 1;
  int phase = (blockIdx.x >= half) ? 1 : 0;
  int r = blockIdx.x - phase * half;
  int s8 = r & 7, g = r >> 3;
  int row = g * 256 + threadIdx.x;
  if (row >= M) return;
  int fg0 = s8 * 8 + phase * 4;
  const unsigned short* P0 = HG + (size_t)(fg0 + 0) * PLANE;
  const unsigned short* P1 = HG + (size_t)(fg0 + 1) * PLANE;
  const unsigned short* P2 = HG + (size_t)(fg0 + 2) * PLANE;
  const unsigned short* P3 = HG + (size_t)(fg0 + 3) * PLANE;
  int start = row_ptr[row], end = row_ptr[row + 1];
  f32x4 a0 = (f32x4)0.f, a1 = (f32x4)0.f, a2 = (f32x4)0.f, a3 = (f32x4)0.f;
#pragma unroll 2
  for (int e = start; e < end; e++) {
    unsigned int p = cvp[e];
    int c4 = (int)(p >> 15) << 2;
    float val = decode_val(p);
    ushort4 x0 = *(const ushort4*)(P0 + c4);
    ushort4 x1 = *(const ushort4*)(P1 + c4);
    ushort4 x2 = *(const ushort4*)(P2 + c4);
    ushort4 x3 = *(const ushort4*)(P3 + c4);
    a0.x = fmaf(val, b2f(x0.x), a0.x); a0.y = fmaf(val, b2f(x0.y), a0.y);
    a0.z = fmaf(val, b2f(x0.z), a0.z); a0.w = fmaf(val, b2f(x0.w), a0.w);
    a1.x = fmaf(val, b2f(x1.x), a1.x); a1.y = fmaf(val, b2f(x1.y), a1.y);
    a1.z = fmaf(val, b2f(x1.z), a1.z); a1.w = fmaf(val, b2f(x1.w), a1.w);
    a2.x = fmaf(val, b2f(x2.x), a2.x); a2.y = fmaf(val, b2f(x2.y), a2.y);
    a2.z = fmaf(val, b2f(x2.z), a2.z); a2.w = fmaf(val, b2f(x2.w), a2.w);
    a3.x = fmaf(val, b2f(x3.x), a3.x); a3.y = fmaf(val, b2f(x3.y), a3.y);
    a3.z = fmaf(val, b2f(x3.z), a3.z); a3.w = fmaf(val, b2f(x3.w), a3.w);
  }
  unsigned short* yp = Y + (size_t)row * N_HID + fg0 * 4;
  ushort4 w;
  w.x = f2bu(fmaxf(a0.x, 0.f)); w.y = f2bu(fmaxf(a0.y, 0.f));
  w.z = f2bu(fmaxf(a0.z, 0.f)); w.w = f2bu(fmaxf(a0.w, 0.f));
  *(ushort4*)(yp + 0) = w;
  w.x = f2bu(fmaxf(a1.x, 0.f)); w.y = f2bu(fmaxf(a1.y, 0.f));
  w.z = f2bu(fmaxf(a1.z, 0.f)); w.w = f2bu(fmaxf(a1.w, 0.f));
  *(ushort4*)(yp + 4) = w;
  w.x = f2bu(fmaxf(a2.x, 0.f)); w.y = f2bu(fmaxf(a2.y, 0.f));
  w.z = f2bu(fmaxf(a2.z, 0.f)); w.w = f2bu(fmaxf(a2.w, 0.f));
  *(ushort4*)(yp + 8) = w;
  w.x = f2bu(fmaxf(a3.x, 0.f)); w.y = f2bu(fmaxf(a3.y, 0.f));
  w.z = f2bu(fmaxf(a3.z, 0.f)); w.w = f2bu(fmaxf(a3.w, 0.f));
  *(ushort4*)(yp + 12) = w;
}

// ---------------------------------------------------------------------------
// GEMM2: O[M,40](bf16) = Hpost[M,256](bf16) @ W2[256,40] + b2; 2 rows/thread.
// ---------------------------------------------------------------------------
__global__ __launch_bounds__(256) void gemm2_kernel(
    const unsigned short* __restrict__ H, const float* __restrict__ W2,
    const float* __restrict__ b2, unsigned short* __restrict__ O, int M) {
  __shared__ float Ws[N_HID * N_CLASS];
  __shared__ float sb2[N_CLASS];
  int tid = threadIdx.x;
  for (int i = tid; i < N_HID * N_CLASS; i += 256) Ws[i] = W2[i];
  if (tid < N_CLASS) sb2[tid] = b2[tid];
  __syncthreads();
  int r0 = (blockIdx.x * 256 + tid) * 2;
  if (r0 >= M) return;
  int r1 = r0 + 1;
  bool has1 = r1 < M;
  float acc0[N_CLASS], acc1[N_CLASS];
#pragma unroll
  for (int n = 0; n < N_CLASS; n++) { acc0[n] = sb2[n]; acc1[n] = sb2[n]; }
  const unsigned short* h0 = H + (size_t)r0 * N_HID;
  const unsigned short* h1 = H + (size_t)(has1 ? r1 : r0) * N_HID;
  for (int k0 = 0; k0 < N_HID; k0 += 8) {
    u16x8 va = *(const u16x8*)(h0 + k0);
    u16x8 vb = *(const u16x8*)(h1 + k0);
#pragma unroll
    for (int j = 0; j < 8; j++) {
      float a0 = b2f(va[j]), a1 = b2f(vb[j]);
      const float* wrow = &Ws[(k0 + j) * N_CLASS];
#pragma unroll
      for (int n = 0; n < N_CLASS; n++) {
        float wv = wrow[n];
        acc0[n] = fmaf(a0, wv, acc0[n]);
        acc1[n] = fmaf(a1, wv, acc1[n]);
      }
    }
  }
  unsigned short* o0 = O + (size_t)r0 * N_CLASS;
#pragma unroll
  for (int n = 0; n < N_CLASS; n += 4) {
    ushort4 p;
    p.x = f2bu(acc0[n]); p.y = f2bu(acc0[n + 1]);
    p.z = f2bu(acc0[n + 2]); p.w = f2bu(acc0[n + 3]);
    *(ushort4*)(o0 + n) = p;
  }
  if (has1) {
    unsigned short* o1 = O + (size_t)r1 * N_CLASS;
#pragma unroll
    for (int n = 0; n < N_CLASS; n += 4) {
      ushort4 p;
      p.x = f2bu(acc1[n]); p.y = f2bu(acc1[n + 1]);
      p.z = f2bu(acc1[n + 2]); p.w = f2bu(acc1[n + 3]);
      *(ushort4*)(o1 + n) = p;
    }
  }
}

// ---------------------------------------------------------------------------
// SPMM2 (F=40, bf16 X, packed cvp) + fused log_softmax: wave/row, unroll 4
// ---------------------------------------------------------------------------
__global__ __launch_bounds__(256) void spmm_csr_40_lsm(
    const int* __restrict__ row_ptr, const unsigned int* __restrict__ cvp,
    const unsigned short* __restrict__ X, float* __restrict__ Out, int M) {
  int wave = (blockIdx.x * 256 + threadIdx.x) >> 6;
  int lane = threadIdx.x & 63;
  if (wave >= M) return;
  int start = row_ptr[wave], end = row_ptr[wave + 1];
  bool act = lane < N_CLASS;
  int ln = act ? lane : 0;
  const unsigned short* Xc = X + ln;
  float acc = 0.f;
  int e = start;
  for (; e + 4 <= end; e += 4) {
    unsigned int p0 = cvp[e], p1 = cvp[e + 1], p2 = cvp[e + 2], p3 = cvp[e + 3];
    unsigned short x0 = Xc[(size_t)(p0 >> 15) * N_CLASS];
    unsigned short x1 = Xc[(size_t)(p1 >> 15) * N_CLASS];
    unsigned short x2 = Xc[(size_t)(p2 >> 15) * N_CLASS];
    unsigned short x3 = Xc[(size_t)(p3 >> 15) * N_CLASS];
    acc = fmaf(decode_val(p0), b2f(x0), acc);
    acc = fmaf(decode_val(p1), b2f(x1), acc);
    acc = fmaf(decode_val(p2), b2f(x2), acc);
    acc = fmaf(decode_val(p3), b2f(x3), acc);
  }
  for (; e < end; e++) {
    unsigned int p0 = cvp[e];
    acc = fmaf(decode_val(p0), b2f(Xc[(size_t)(p0 >> 15) * N_CLASS]), acc);
  }
  float mv = act ? acc : -INFINITY;
#pragma unroll
  for (int off = 32; off; off >>= 1) mv = fmaxf(mv, __shfl_xor(mv, off));
  float ex = act ? expf(acc - mv) : 0.f;
  float s = ex;
#pragma unroll
  for (int off = 32; off; off >>= 1) s += __shfl_xor(s, off);
  float lse = mv + logf(s);
  if (act) Out[(size_t)wave * N_CLASS + lane] = acc - lse;
}

// ---------------------------------------------------------------------------
extern "C" void kernel_launch(void* const* d_in, const int* in_sizes, int n_in,
                              void* d_out, int out_size, void* d_ws, size_t ws_size,
                              hipStream_t stream) {
  const float* feat = (const float*)d_in[0];
  const int* er     = (const int*)d_in[1];
  const int* ec     = (const int*)d_in[2];
  const float* ev   = (const float*)d_in[3];
  const float* W1   = (const float*)d_in[4];
  const float* b1   = (const float*)d_in[5];
  const float* W2   = (const float*)d_in[6];
  const float* b2   = (const float*)d_in[7];
  float* out = (float*)d_out;
  const int M = N_NODES;
  const int E = in_sizes[1];

  char* ws = (char*)d_ws;
  unsigned short* hg    = (unsigned short*)(ws);                 // 51.2 MB grouped
  unsigned short* hpost = (unsigned short*)(ws + 51200000);      // 51.2 MB
  unsigned short* o     = (unsigned short*)(ws + 102400000);     // 8 MB
  int* row_ptr          = (int*)(ws + 110400000);                // 400,004 B
  int* cursor           = (int*)(ws + 110800016);                // 400,000 B
  int* bcur             = (int*)(ws + 111200016);                // 32 B
  int* bsum             = (int*)(ws + 111200064);                // 512 B
  unsigned int* cvp     = (unsigned int*)(ws + 111200576);       // 12.8 MB
  unsigned short* W1Tsw = (unsigned short*)(ws + 124000576);     // 256 KB
  unsigned long long* buckets = (unsigned long long*)(ws + 128000000);  // 28.7 MB

  const int NB1 = (M + 1023) / 1024;  // 98

  cast_w1<<<64, 256, 0, stream>>>(W1, W1Tsw);
  (void)hipMemsetAsync(cursor, 0, 400048, stream);  // cursor + bcur
  hist_kernel<<<1024, 256, 0, stream>>>(er, cursor, E);
  scan1_kernel<<<NB1, 1024, 0, stream>>>(cursor, bsum, M);
  scan2_kernel<<<1, 64, 0, stream>>>(bsum, row_ptr, NB1, M);
  scan3_kernel<<<(M + 255) / 256, 256, 0, stream>>>(cursor, bsum, row_ptr, M);
  bin_kernel<<<512, 256, 0, stream>>>(er, ec, ev, bcur, buckets, E);
  scatter2_kernel<<<2048, 256, 0, stream>>>(buckets, bcur, cursor, cvp);
  gemm1_mfma<<<(M + 127) / 128, 512, 0, stream>>>(feat, W1Tsw, b1, hg, M);
  {
    int half = 8 * ((M + 255) / 256);  // 8 * 391
    spmm_fs<<<2 * half, 256, 0, stream>>>(row_ptr, cvp, hg, hpost, M);
  }
  gemm2_kernel<<<(M + 511) / 512, 256, 0, stream>>>(hpost, W2, b2, o, M);
  spmm_csr_40_lsm<<<(M + 3) / 4, 256, 0, stream>>>(row_ptr, cvp, o, out, M);
}

// Round 8
// 705.651 us; speedup vs baseline: 2.5523x; 2.5523x over previous
//
#include <hip/hip_runtime.h>
#include <hip/hip_bf16.h>
#include <math.h>

#define N_NODES 100000
#define N_FEAT 500
#define N_HID 256
#define N_CLASS 40

typedef float f32x4 __attribute__((ext_vector_type(4)));
typedef float f32x2 __attribute__((ext_vector_type(2)));
typedef int i32x4 __attribute__((ext_vector_type(4)));
typedef unsigned int u32x4 __attribute__((ext_vector_type(4)));
typedef short short8 __attribute__((ext_vector_type(8)));
typedef unsigned short u16x8 __attribute__((ext_vector_type(8)));

__device__ __forceinline__ float b2f(unsigned short u) {
  union { unsigned int i; float f; } c; c.i = ((unsigned int)u) << 16; return c.f;
}
__device__ __forceinline__ unsigned short f2bu(float x) {
  __hip_bfloat16 b = __float2bfloat16(x);
  union { __hip_bfloat16 b; unsigned short u; } c; c.b = b; return c.u;
}
__device__ __forceinline__ float decode_val(unsigned int p) {
  union { unsigned int i; float f; } c; c.i = (p & 0x7FFFu) << 17; return c.f;
}
__device__ __forceinline__ unsigned char f2fp8(float x) {
  return (unsigned char)(__builtin_amdgcn_cvt_pk_fp8_f32(x, x, 0, false) & 0xFF);
}
__device__ __forceinline__ void gload_lds16(const void* gptr, void* lptr) {
  __builtin_amdgcn_global_load_lds(
      (const __attribute__((address_space(1))) unsigned int*)gptr,
      (__attribute__((address_space(3))) unsigned int*)lptr, 16, 0, 0);
}

// ---------------------------------------------------------------------------
// prep: (blocks 0..63 also cast W1 -> W1T_sw bf16 swizzled) + histogram of er
// + pack cvps[i] = col<<15 | bf16(val)>>1 in edge order.
// ---------------------------------------------------------------------------
__global__ __launch_bounds__(256) void prep_kernel(
    const float* __restrict__ W1, unsigned short* __restrict__ Bsw,
    const int* __restrict__ er, const int* __restrict__ ec,
    const float* __restrict__ ev, int* __restrict__ cnt,
    unsigned int* __restrict__ cvps, int E) {
  if (blockIdx.x < 64) {
    int t = blockIdx.x * 256 + threadIdx.x;  // 16384 = 256 cols x 64 chunks
    int col = t >> 6, ch = t & 63;
    int g = ch >> 3, c = ch & 7;
    int c_src = c ^ (col & 7);
    int k = g * 64 + c_src * 8;
    u16x8 o;
#pragma unroll
    for (int j = 0; j < 8; j++) {
      int kk = k + j;
      o[j] = (kk < N_FEAT) ? f2bu(W1[(size_t)kk * N_HID + col]) : (unsigned short)0;
    }
    *(u16x8*)(Bsw + (size_t)col * 512 + g * 64 + c * 8) = o;
  }
  int nv = E >> 2;
  int t = blockIdx.x * 256 + threadIdx.x;
  int nthr = gridDim.x * 256;
  const i32x4* er4 = (const i32x4*)er;
  const i32x4* ec4 = (const i32x4*)ec;
  const f32x4* ev4 = (const f32x4*)ev;
  for (int i = t; i < nv; i += nthr) {
    i32x4 r = __builtin_nontemporal_load(&er4[i]);
    i32x4 c = __builtin_nontemporal_load(&ec4[i]);
    f32x4 v = __builtin_nontemporal_load(&ev4[i]);
    atomicAdd(&cnt[r.x], 1);
    atomicAdd(&cnt[r.y], 1);
    atomicAdd(&cnt[r.z], 1);
    atomicAdd(&cnt[r.w], 1);
    u32x4 pk;
    pk.x = ((unsigned int)c.x << 15) | ((unsigned int)f2bu(v.x) >> 1);
    pk.y = ((unsigned int)c.y << 15) | ((unsigned int)f2bu(v.y) >> 1);
    pk.z = ((unsigned int)c.z << 15) | ((unsigned int)f2bu(v.z) >> 1);
    pk.w = ((unsigned int)c.w << 15) | ((unsigned int)f2bu(v.w) >> 1);
    __builtin_nontemporal_store(pk, (u32x4*)(cvps + 4 * (size_t)i));
  }
  int tail = nv << 2;
  if (blockIdx.x == 0 && threadIdx.x < E - tail) {
    int i = tail + threadIdx.x;
    atomicAdd(&cnt[er[i]], 1);
    cvps[i] = ((unsigned int)ec[i] << 15) | ((unsigned int)f2bu(ev[i]) >> 1);
  }
}

// ---------------------------------------------------------------------------
// GEMM1 (bf16 MFMA): H[M,256] = A[M,500] @ W1 + b1, fp8-e4m3 out.
// ---------------------------------------------------------------------------
__global__ __launch_bounds__(512) void gemm1_mfma(
    const float* __restrict__ A, const unsigned short* __restrict__ Bsw,
    const float* __restrict__ b1, unsigned char* __restrict__ H, int M) {
  __shared__ __align__(16) char smem[49152];
  char* sA = smem;
  char* sB = smem + 16384;
  int tid = threadIdx.x;
  int lane = tid & 63, w = tid >> 6;
  int wr = w >> 2, wc = w & 3;
  int bm = blockIdx.x * 128;

  f32x4 acc[4][4];
#pragma unroll
  for (int m = 0; m < 4; m++)
#pragma unroll
    for (int n = 0; n < 4; n++) acc[m][n] = (f32x4)0.f;

  for (int s = 0; s < 8; s++) {
    int k0 = s * 64;
#pragma unroll
    for (int i = 0; i < 4; i++) {
      int f4 = i * 512 + tid;
      int row = f4 >> 4, cidx = f4 & 15;
      int grow = bm + row;
      int k = k0 + cidx * 4;
      float4 v = make_float4(0.f, 0.f, 0.f, 0.f);
      if (grow < M && k < N_FEAT) v = *(const float4*)(A + (size_t)grow * N_FEAT + k);
      ushort4 u;
      u.x = f2bu(v.x); u.y = f2bu(v.y); u.z = f2bu(v.z); u.w = f2bu(v.w);
      int chunk = cidx >> 1, sub = cidx & 1;
      int byte = row * 128 + (((chunk ^ (row & 7))) << 4) + (sub << 3);
      *(ushort4*)(sA + byte) = u;
    }
#pragma unroll
    for (int j = 0; j < 4; j++) {
      int base = j * 8192 + w * 1024;
      int L = base + lane * 16;
      int col = L >> 7, c = (L >> 4) & 7;
      const char* g = (const char*)Bsw + (size_t)col * 1024 + s * 128 + c * 16;
      gload_lds16(g, sB + base);
    }
    __syncthreads();
#pragma unroll
    for (int kk = 0; kk < 2; kk++) {
      int cw = kk * 4 + (lane >> 4);
      short8 af[4], bg[4];
#pragma unroll
      for (int m = 0; m < 4; m++) {
        int ar = wr * 64 + m * 16 + (lane & 15);
        af[m] = *(const short8*)(sA + ar * 128 + ((cw ^ (ar & 7)) << 4));
      }
#pragma unroll
      for (int n = 0; n < 4; n++) {
        int bc = wc * 64 + n * 16 + (lane & 15);
        bg[n] = *(const short8*)(sB + bc * 128 + ((cw ^ (bc & 7)) << 4));
      }
#pragma unroll
      for (int m = 0; m < 4; m++)
#pragma unroll
        for (int n = 0; n < 4; n++)
          acc[m][n] = __builtin_amdgcn_mfma_f32_16x16x32_bf16(af[m], bg[n], acc[m][n], 0, 0, 0);
    }
    __syncthreads();
  }

  float bias[4];
#pragma unroll
  for (int n = 0; n < 4; n++) bias[n] = b1[wc * 64 + n * 16 + (lane & 15)];
#pragma unroll
  for (int m = 0; m < 4; m++) {
#pragma unroll
    for (int r = 0; r < 4; r++) {
      int row = bm + wr * 64 + m * 16 + ((lane >> 4) << 2) + r;
      if (row < M) {
#pragma unroll
        for (int n = 0; n < 4; n++) {
          int col = wc * 64 + n * 16 + (lane & 15);
          H[(size_t)row * N_HID + col] = f2fp8(acc[m][n][r] + bias[n]);
        }
      }
    }
  }
}

// ---------------------------------------------------------------------------
// scans (unchanged)
// ---------------------------------------------------------------------------
__global__ __launch_bounds__(1024) void scan1_kernel(
    int* __restrict__ cnt, int* __restrict__ bsum, int n) {
  __shared__ int wsum[16];
  int tid = threadIdx.x, lane = tid & 63, wid = tid >> 6;
  int i = blockIdx.x * 1024 + tid;
  int v = (i < n) ? cnt[i] : 0;
  int x = v;
#pragma unroll
  for (int off = 1; off < 64; off <<= 1) {
    int t = __shfl_up(x, off);
    if (lane >= off) x += t;
  }
  if (lane == 63) wsum[wid] = x;
  __syncthreads();
  if (tid < 16) {
    int ws = wsum[tid];
#pragma unroll
    for (int off = 1; off < 16; off <<= 1) {
      int t = __shfl_up(ws, off);
      if (tid >= off) ws += t;
    }
    wsum[tid] = ws;
  }
  __syncthreads();
  int excl = (wid ? wsum[wid - 1] : 0) + x - v;
  if (i < n) cnt[i] = excl;
  if (tid == 0) bsum[blockIdx.x] = wsum[15];
}

__global__ __launch_bounds__(64) void scan2_kernel(
    int* __restrict__ bsum, int* __restrict__ row_ptr, int nb, int n) {
  int lane = threadIdx.x;
  int carry = 0;
  for (int base = 0; base < nb; base += 64) {
    int i = base + lane;
    int v = (i < nb) ? bsum[i] : 0;
    int x = v;
#pragma unroll
    for (int off = 1; off < 64; off <<= 1) {
      int t = __shfl_up(x, off);
      if (lane >= off) x += t;
    }
    if (i < nb) bsum[i] = carry + x - v;
    carry += __shfl(x, 63);
  }
  if (lane == 0) row_ptr[n] = carry;
}

__global__ __launch_bounds__(256) void scan3_kernel(
    int* __restrict__ cnt, const int* __restrict__ bsum,
    int* __restrict__ row_ptr, int n) {
  int i = blockIdx.x * 256 + threadIdx.x;
  if (i >= n) return;
  int v = cnt[i] + bsum[i >> 10];
  cnt[i] = v;
  row_ptr[i] = v;
}

// ---------------------------------------------------------------------------
// XCD-sliced scatter (round-6 validated): block b handles slice (row>>9)&7
// == b&7; reads er + packed cvps sequentially (8x re-read, L3-resident),
// writes cvp[pos] 4 B within its own XCD's L2.
// ---------------------------------------------------------------------------
__global__ __launch_bounds__(256) void scatter_kernel(
    const int* __restrict__ er, const unsigned int* __restrict__ cvps,
    int* __restrict__ cursor, unsigned int* __restrict__ cvp, int E) {
  int s = blockIdx.x & 7;
  int g = blockIdx.x >> 3;
  int ngrp = gridDim.x >> 3;
  int nv = E >> 2;
  const i32x4* er4 = (const i32x4*)er;
  const u32x4* cv4 = (const u32x4*)cvps;
  for (int i = g * 256 + threadIdx.x; i < nv; i += ngrp * 256) {
    i32x4 r = __builtin_nontemporal_load(&er4[i]);
    u32x4 p = __builtin_nontemporal_load(&cv4[i]);
    if (((r.x >> 9) & 7) == s) cvp[atomicAdd(&cursor[r.x], 1)] = p.x;
    if (((r.y >> 9) & 7) == s) cvp[atomicAdd(&cursor[r.y], 1)] = p.y;
    if (((r.z >> 9) & 7) == s) cvp[atomicAdd(&cursor[r.z], 1)] = p.z;
    if (((r.w >> 9) & 7) == s) cvp[atomicAdd(&cursor[r.w], 1)] = p.w;
  }
  int tail = nv << 2;
  if (blockIdx.x == 0 && threadIdx.x < E - tail) {
    int i = tail + threadIdx.x;
    cvp[atomicAdd(&cursor[er[i]], 1)] = cvps[i];
  }
}

// ---------------------------------------------------------------------------
// SPMM1 (CSR, F=256, fp8 X -> bf16 Y, fused ReLU): wave per row, 2 edges per
// step (half-wave each), 8 feats x 8 B gather per lane, HW fp8->f32 decode.
// ---------------------------------------------------------------------------
__global__ __launch_bounds__(256) void spmm_fp8(
    const int* __restrict__ row_ptr, const unsigned int* __restrict__ cvp,
    const unsigned char* __restrict__ X, unsigned short* __restrict__ Y, int M) {
  int wave = (blockIdx.x * 256 + threadIdx.x) >> 6;
  int lane = threadIdx.x & 63;
  if (wave >= M) return;
  int start = row_ptr[wave], end = row_ptr[wave + 1];
  int hf = lane >> 5, fl = lane & 31;
  float a0 = 0.f, a1 = 0.f, a2 = 0.f, a3 = 0.f;
  float a4 = 0.f, a5 = 0.f, a6 = 0.f, a7 = 0.f;
  const unsigned char* Xf = X + fl * 8;
#pragma unroll 2
  for (int e = start; e < end; e += 2) {
    int ei = e + hf;
    unsigned int p = (ei < end) ? cvp[ei] : 0u;
    float val = decode_val(p);
    size_t col = (size_t)(p >> 15);
    uint2 d = *(const uint2*)(Xf + col * N_HID);
    f32x2 f01 = __builtin_amdgcn_cvt_pk_f32_fp8(d.x, false);
    f32x2 f23 = __builtin_amdgcn_cvt_pk_f32_fp8(d.x, true);
    f32x2 f45 = __builtin_amdgcn_cvt_pk_f32_fp8(d.y, false);
    f32x2 f67 = __builtin_amdgcn_cvt_pk_f32_fp8(d.y, true);
    a0 = fmaf(val, f01.x, a0); a1 = fmaf(val, f01.y, a1);
    a2 = fmaf(val, f23.x, a2); a3 = fmaf(val, f23.y, a3);
    a4 = fmaf(val, f45.x, a4); a5 = fmaf(val, f45.y, a5);
    a6 = fmaf(val, f67.x, a6); a7 = fmaf(val, f67.y, a7);
  }
  a0 += __shfl_xor(a0, 32); a1 += __shfl_xor(a1, 32);
  a2 += __shfl_xor(a2, 32); a3 += __shfl_xor(a3, 32);
  a4 += __shfl_xor(a4, 32); a5 += __shfl_xor(a5, 32);
  a6 += __shfl_xor(a6, 32); a7 += __shfl_xor(a7, 32);
  if (hf == 0) {
    u16x8 o;
    o[0] = f2bu(fmaxf(a0, 0.f)); o[1] = f2bu(fmaxf(a1, 0.f));
    o[2] = f2bu(fmaxf(a2, 0.f)); o[3] = f2bu(fmaxf(a3, 0.f));
    o[4] = f2bu(fmaxf(a4, 0.f)); o[5] = f2bu(fmaxf(a5, 0.f));
    o[6] = f2bu(fmaxf(a6, 0.f)); o[7] = f2bu(fmaxf(a7, 0.f));
    *(u16x8*)(Y + (size_t)wave * N_HID + fl * 8) = o;
  }
}

// ---------------------------------------------------------------------------
// GEMM2: O[M,40](bf16) = Hpost[M,256](bf16) @ W2[256,40] + b2; 2 rows/thread.
// ---------------------------------------------------------------------------
__global__ __launch_bounds__(256) void gemm2_kernel(
    const unsigned short* __restrict__ H, const float* __restrict__ W2,
    const float* __restrict__ b2, unsigned short* __restrict__ O, int M) {
  __shared__ float Ws[N_HID * N_CLASS];
  __shared__ float sb2[N_CLASS];
  int tid = threadIdx.x;
  for (int i = tid; i < N_HID * N_CLASS; i += 256) Ws[i] = W2[i];
  if (tid < N_CLASS) sb2[tid] = b2[tid];
  __syncthreads();
  int r0 = (blockIdx.x * 256 + tid) * 2;
  if (r0 >= M) return;
  int r1 = r0 + 1;
  bool has1 = r1 < M;
  float acc0[N_CLASS], acc1[N_CLASS];
#pragma unroll
  for (int n = 0; n < N_CLASS; n++) { acc0[n] = sb2[n]; acc1[n] = sb2[n]; }
  const unsigned short* h0 = H + (size_t)r0 * N_HID;
  const unsigned short* h1 = H + (size_t)(has1 ? r1 : r0) * N_HID;
  for (int k0 = 0; k0 < N_HID; k0 += 8) {
    u16x8 va = *(const u16x8*)(h0 + k0);
    u16x8 vb = *(const u16x8*)(h1 + k0);
#pragma unroll
    for (int j = 0; j < 8; j++) {
      float a0 = b2f(va[j]), a1 = b2f(vb[j]);
      const float* wrow = &Ws[(k0 + j) * N_CLASS];
#pragma unroll
      for (int n = 0; n < N_CLASS; n++) {
        float wv = wrow[n];
        acc0[n] = fmaf(a0, wv, acc0[n]);
        acc1[n] = fmaf(a1, wv, acc1[n]);
      }
    }
  }
  unsigned short* o0 = O + (size_t)r0 * N_CLASS;
#pragma unroll
  for (int n = 0; n < N_CLASS; n += 4) {
    ushort4 p;
    p.x = f2bu(acc0[n]); p.y = f2bu(acc0[n + 1]);
    p.z = f2bu(acc0[n + 2]); p.w = f2bu(acc0[n + 3]);
    *(ushort4*)(o0 + n) = p;
  }
  if (has1) {
    unsigned short* o1 = O + (size_t)r1 * N_CLASS;
#pragma unroll
    for (int n = 0; n < N_CLASS; n += 4) {
      ushort4 p;
      p.x = f2bu(acc1[n]); p.y = f2bu(acc1[n + 1]);
      p.z = f2bu(acc1[n + 2]); p.w = f2bu(acc1[n + 3]);
      *(ushort4*)(o1 + n) = p;
    }
  }
}

// ---------------------------------------------------------------------------
// SPMM2 (F=40, bf16 X, packed cvp) + fused log_softmax: wave/row, unroll 4
// ---------------------------------------------------------------------------
__global__ __launch_bounds__(256) void spmm_csr_40_lsm(
    const int* __restrict__ row_ptr, const unsigned int* __restrict__ cvp,
    const unsigned short* __restrict__ X, float* __restrict__ Out, int M) {
  int wave = (blockIdx.x * 256 + threadIdx.x) >> 6;
  int lane = threadIdx.x & 63;
  if (wave >= M) return;
  int start = row_ptr[wave], end = row_ptr[wave + 1];
  bool act = lane < N_CLASS;
  int ln = act ? lane : 0;
  const unsigned short* Xc = X + ln;
  float acc = 0.f;
  int e = start;
  for (; e + 4 <= end; e += 4) {
    unsigned int p0 = cvp[e], p1 = cvp[e + 1], p2 = cvp[e + 2], p3 = cvp[e + 3];
    unsigned short x0 = Xc[(size_t)(p0 >> 15) * N_CLASS];
    unsigned short x1 = Xc[(size_t)(p1 >> 15) * N_CLASS];
    unsigned short x2 = Xc[(size_t)(p2 >> 15) * N_CLASS];
    unsigned short x3 = Xc[(size_t)(p3 >> 15) * N_CLASS];
    acc = fmaf(decode_val(p0), b2f(x0), acc);
    acc = fmaf(decode_val(p1), b2f(x1), acc);
    acc = fmaf(decode_val(p2), b2f(x2), acc);
    acc = fmaf(decode_val(p3), b2f(x3), acc);
  }
  for (; e < end; e++) {
    unsigned int p0 = cvp[e];
    acc = fmaf(decode_val(p0), b2f(Xc[(size_t)(p0 >> 15) * N_CLASS]), acc);
  }
  float mv = act ? acc : -INFINITY;
#pragma unroll
  for (int off = 32; off; off >>= 1) mv = fmaxf(mv, __shfl_xor(mv, off));
  float ex = act ? expf(acc - mv) : 0.f;
  float s = ex;
#pragma unroll
  for (int off = 32; off; off >>= 1) s += __shfl_xor(s, off);
  float lse = mv + logf(s);
  if (act) Out[(size_t)wave * N_CLASS + lane] = acc - lse;
}

// ---------------------------------------------------------------------------
extern "C" void kernel_launch(void* const* d_in, const int* in_sizes, int n_in,
                              void* d_out, int out_size, void* d_ws, size_t ws_size,
                              hipStream_t stream) {
  const float* feat = (const float*)d_in[0];
  const int* er     = (const int*)d_in[1];
  const int* ec     = (const int*)d_in[2];
  const float* ev   = (const float*)d_in[3];
  const float* W1   = (const float*)d_in[4];
  const float* b1   = (const float*)d_in[5];
  const float* W2   = (const float*)d_in[6];
  const float* b2   = (const float*)d_in[7];
  float* out = (float*)d_out;
  const int M = N_NODES;
  const int E = in_sizes[1];

  char* ws = (char*)d_ws;
  unsigned char* h      = (unsigned char*)(ws);                  // 25.6 MB fp8
  unsigned short* hpost = (unsigned short*)(ws + 25600000);      // 51.2 MB bf16
  unsigned short* o     = (unsigned short*)(ws + 76800000);      // 8 MB bf16
  int* row_ptr          = (int*)(ws + 84800000);                 // 400,004 B
  int* cursor           = (int*)(ws + 85200016);                 // 400,000 B
  int* bsum             = (int*)(ws + 85600016);                 // 512 B
  unsigned int* cvp     = (unsigned int*)(ws + 85600528);        // 12.8 MB
  unsigned int* cvps    = (unsigned int*)(ws + 98400528);        // 12.8 MB
  unsigned short* W1Tsw = (unsigned short*)(ws + 111200528);     // 256 KB

  const int NB1 = (M + 1023) / 1024;  // 98

  (void)hipMemsetAsync(cursor, 0, (size_t)M * sizeof(int), stream);
  prep_kernel<<<1024, 256, 0, stream>>>(W1, W1Tsw, er, ec, ev, cursor, cvps, E);
  scan1_kernel<<<NB1, 1024, 0, stream>>>(cursor, bsum, M);
  scan2_kernel<<<1, 64, 0, stream>>>(bsum, row_ptr, NB1, M);
  scan3_kernel<<<(M + 255) / 256, 256, 0, stream>>>(cursor, bsum, row_ptr, M);
  scatter_kernel<<<2048, 256, 0, stream>>>(er, cvps, cursor, cvp, E);
  gemm1_mfma<<<(M + 127) / 128, 512, 0, stream>>>(feat, W1Tsw, b1, h, M);
  spmm_fp8<<<(M + 3) / 4, 256, 0, stream>>>(row_ptr, cvp, h, hpost, M);
  gemm2_kernel<<<(M + 511) / 512, 256, 0, stream>>>(hpost, W2, b2, o, M);
  spmm_csr_40_lsm<<<(M + 3) / 4, 256, 0, stream>>>(row_ptr, cvp, o, out, M);
}

// Round 9
// 667.988 us; speedup vs baseline: 2.6962x; 1.0564x over previous
//
#include <hip/hip_runtime.h>
#include <hip/hip_bf16.h>
#include <math.h>

#define N_NODES 100000
#define N_FEAT 500
#define N_HID 256
#define N_CLASS 40

typedef float f32x4 __attribute__((ext_vector_type(4)));
typedef float f32x2 __attribute__((ext_vector_type(2)));
typedef int i32x4 __attribute__((ext_vector_type(4)));
typedef unsigned int u32x4 __attribute__((ext_vector_type(4)));
typedef short short8 __attribute__((ext_vector_type(8)));
typedef unsigned short u16x8 __attribute__((ext_vector_type(8)));

__device__ __forceinline__ float b2f(unsigned short u) {
  union { unsigned int i; float f; } c; c.i = ((unsigned int)u) << 16; return c.f;
}
__device__ __forceinline__ unsigned short f2bu(float x) {
  __hip_bfloat16 b = __float2bfloat16(x);
  union { __hip_bfloat16 b; unsigned short u; } c; c.b = b; return c.u;
}
__device__ __forceinline__ float decode_val(unsigned int p) {
  union { unsigned int i; float f; } c; c.i = (p & 0x7FFFu) << 17; return c.f;
}
__device__ __forceinline__ unsigned char f2fp8(float x) {
  return (unsigned char)(__builtin_amdgcn_cvt_pk_fp8_f32(x, x, 0, false) & 0xFF);
}
__device__ __forceinline__ void gload_lds16(const void* gptr, void* lptr) {
  __builtin_amdgcn_global_load_lds(
      (const __attribute__((address_space(1))) unsigned int*)gptr,
      (__attribute__((address_space(3))) unsigned int*)lptr, 16, 0, 0);
}

// ---------------------------------------------------------------------------
// prep: (blocks 0..63 also cast W1 -> W1T_sw bf16 swizzled) + histogram of er
// + pack cvps[i] = col<<15 | bf16(val)>>1 in edge order.
// ---------------------------------------------------------------------------
__global__ __launch_bounds__(256) void prep_kernel(
    const float* __restrict__ W1, unsigned short* __restrict__ Bsw,
    const int* __restrict__ er, const int* __restrict__ ec,
    const float* __restrict__ ev, int* __restrict__ cnt,
    unsigned int* __restrict__ cvps, int E) {
  if (blockIdx.x < 64) {
    int t = blockIdx.x * 256 + threadIdx.x;
    int col = t >> 6, ch = t & 63;
    int g = ch >> 3, c = ch & 7;
    int c_src = c ^ (col & 7);
    int k = g * 64 + c_src * 8;
    u16x8 o;
#pragma unroll
    for (int j = 0; j < 8; j++) {
      int kk = k + j;
      o[j] = (kk < N_FEAT) ? f2bu(W1[(size_t)kk * N_HID + col]) : (unsigned short)0;
    }
    *(u16x8*)(Bsw + (size_t)col * 512 + g * 64 + c * 8) = o;
  }
  int nv = E >> 2;
  int t = blockIdx.x * 256 + threadIdx.x;
  int nthr = gridDim.x * 256;
  const i32x4* er4 = (const i32x4*)er;
  const i32x4* ec4 = (const i32x4*)ec;
  const f32x4* ev4 = (const f32x4*)ev;
  for (int i = t; i < nv; i += nthr) {
    i32x4 r = __builtin_nontemporal_load(&er4[i]);
    i32x4 c = __builtin_nontemporal_load(&ec4[i]);
    f32x4 v = __builtin_nontemporal_load(&ev4[i]);
    atomicAdd(&cnt[r.x], 1);
    atomicAdd(&cnt[r.y], 1);
    atomicAdd(&cnt[r.z], 1);
    atomicAdd(&cnt[r.w], 1);
    u32x4 pk;
    pk.x = ((unsigned int)c.x << 15) | ((unsigned int)f2bu(v.x) >> 1);
    pk.y = ((unsigned int)c.y << 15) | ((unsigned int)f2bu(v.y) >> 1);
    pk.z = ((unsigned int)c.z << 15) | ((unsigned int)f2bu(v.z) >> 1);
    pk.w = ((unsigned int)c.w << 15) | ((unsigned int)f2bu(v.w) >> 1);
    __builtin_nontemporal_store(pk, (u32x4*)(cvps + 4 * (size_t)i));
  }
  int tail = nv << 2;
  if (blockIdx.x == 0 && threadIdx.x < E - tail) {
    int i = tail + threadIdx.x;
    atomicAdd(&cnt[er[i]], 1);
    cvps[i] = ((unsigned int)ec[i] << 15) | ((unsigned int)f2bu(ev[i]) >> 1);
  }
}

// ---------------------------------------------------------------------------
// GEMM1 (bf16 MFMA): H[M,256] = A[M,500] @ W1 + b1, fp8-e4m3 out.
// BM=64, BN=256, BK=64; 256 threads = 4 waves (1x4); 40 KB LDS -> ~4 blk/CU.
// ---------------------------------------------------------------------------
__global__ __launch_bounds__(256) void gemm1_mfma(
    const float* __restrict__ A, const unsigned short* __restrict__ Bsw,
    const float* __restrict__ b1, unsigned char* __restrict__ H, int M) {
  __shared__ __align__(16) char smem[40960];
  char* sA = smem;            // [64 rows][128 B]
  char* sB = smem + 8192;     // [256 cols][128 B]
  int tid = threadIdx.x;
  int lane = tid & 63, w = tid >> 6;  // w = 0..3
  int wc = w;
  int bm = blockIdx.x * 64;

  f32x4 acc[4][4];
#pragma unroll
  for (int m = 0; m < 4; m++)
#pragma unroll
    for (int n = 0; n < 4; n++) acc[m][n] = (f32x4)0.f;

  for (int s = 0; s < 8; s++) {
    int k0 = s * 64;
    // stage A: 64 rows x 16 float4 = 1024 / 256 thr = 4 each; cvt; swz ds_write
#pragma unroll
    for (int i = 0; i < 4; i++) {
      int f4 = i * 256 + tid;
      int row = f4 >> 4, cidx = f4 & 15;
      int grow = bm + row;
      int k = k0 + cidx * 4;
      float4 v = make_float4(0.f, 0.f, 0.f, 0.f);
      if (grow < M && k < N_FEAT) v = *(const float4*)(A + (size_t)grow * N_FEAT + k);
      ushort4 u;
      u.x = f2bu(v.x); u.y = f2bu(v.y); u.z = f2bu(v.z); u.w = f2bu(v.w);
      int chunk = cidx >> 1, sub = cidx & 1;
      int byte = row * 128 + (((chunk ^ (row & 7))) << 4) + (sub << 3);
      *(ushort4*)(sA + byte) = u;
    }
    // stage B: 32 KB / (256 thr * 16 B) = 8 gload_lds each (linear dest)
#pragma unroll
    for (int j = 0; j < 8; j++) {
      int base = j * 4096 + w * 1024;
      int L = base + lane * 16;
      int col = L >> 7, c = (L >> 4) & 7;
      const char* g = (const char*)Bsw + (size_t)col * 1024 + s * 128 + c * 16;
      gload_lds16(g, sB + base);
    }
    __syncthreads();
#pragma unroll
    for (int kk = 0; kk < 2; kk++) {
      int cw = kk * 4 + (lane >> 4);
      short8 af[4], bg[4];
#pragma unroll
      for (int m = 0; m < 4; m++) {
        int ar = m * 16 + (lane & 15);
        af[m] = *(const short8*)(sA + ar * 128 + ((cw ^ (ar & 7)) << 4));
      }
#pragma unroll
      for (int n = 0; n < 4; n++) {
        int bc = wc * 64 + n * 16 + (lane & 15);
        bg[n] = *(const short8*)(sB + bc * 128 + ((cw ^ (bc & 7)) << 4));
      }
#pragma unroll
      for (int m = 0; m < 4; m++)
#pragma unroll
        for (int n = 0; n < 4; n++)
          acc[m][n] = __builtin_amdgcn_mfma_f32_16x16x32_bf16(af[m], bg[n], acc[m][n], 0, 0, 0);
    }
    __syncthreads();
  }

  float bias[4];
#pragma unroll
  for (int n = 0; n < 4; n++) bias[n] = b1[wc * 64 + n * 16 + (lane & 15)];
#pragma unroll
  for (int m = 0; m < 4; m++) {
#pragma unroll
    for (int r = 0; r < 4; r++) {
      int row = bm + m * 16 + ((lane >> 4) << 2) + r;
      if (row < M) {
#pragma unroll
        for (int n = 0; n < 4; n++) {
          int col = wc * 64 + n * 16 + (lane & 15);
          H[(size_t)row * N_HID + col] = f2fp8(acc[m][n][r] + bias[n]);
        }
      }
    }
  }
}

// ---------------------------------------------------------------------------
// scans (unchanged)
// ---------------------------------------------------------------------------
__global__ __launch_bounds__(1024) void scan1_kernel(
    int* __restrict__ cnt, int* __restrict__ bsum, int n) {
  __shared__ int wsum[16];
  int tid = threadIdx.x, lane = tid & 63, wid = tid >> 6;
  int i = blockIdx.x * 1024 + tid;
  int v = (i < n) ? cnt[i] : 0;
  int x = v;
#pragma unroll
  for (int off = 1; off < 64; off <<= 1) {
    int t = __shfl_up(x, off);
    if (lane >= off) x += t;
  }
  if (lane == 63) wsum[wid] = x;
  __syncthreads();
  if (tid < 16) {
    int ws = wsum[tid];
#pragma unroll
    for (int off = 1; off < 16; off <<= 1) {
      int t = __shfl_up(ws, off);
      if (tid >= off) ws += t;
    }
    wsum[tid] = ws;
  }
  __syncthreads();
  int excl = (wid ? wsum[wid - 1] : 0) + x - v;
  if (i < n) cnt[i] = excl;
  if (tid == 0) bsum[blockIdx.x] = wsum[15];
}

__global__ __launch_bounds__(64) void scan2_kernel(
    int* __restrict__ bsum, int* __restrict__ row_ptr, int nb, int n) {
  int lane = threadIdx.x;
  int carry = 0;
  for (int base = 0; base < nb; base += 64) {
    int i = base + lane;
    int v = (i < nb) ? bsum[i] : 0;
    int x = v;
#pragma unroll
    for (int off = 1; off < 64; off <<= 1) {
      int t = __shfl_up(x, off);
      if (lane >= off) x += t;
    }
    if (i < nb) bsum[i] = carry + x - v;
    carry += __shfl(x, 63);
  }
  if (lane == 0) row_ptr[n] = carry;
}

__global__ __launch_bounds__(256) void scan3_kernel(
    int* __restrict__ cnt, const int* __restrict__ bsum,
    int* __restrict__ row_ptr, int n) {
  int i = blockIdx.x * 256 + threadIdx.x;
  if (i >= n) return;
  int v = cnt[i] + bsum[i >> 10];
  cnt[i] = v;
  row_ptr[i] = v;
}

// ---------------------------------------------------------------------------
// XCD-sliced scatter (unchanged this round)
// ---------------------------------------------------------------------------
__global__ __launch_bounds__(256) void scatter_kernel(
    const int* __restrict__ er, const unsigned int* __restrict__ cvps,
    int* __restrict__ cursor, unsigned int* __restrict__ cvp, int E) {
  int s = blockIdx.x & 7;
  int g = blockIdx.x >> 3;
  int ngrp = gridDim.x >> 3;
  int nv = E >> 2;
  const i32x4* er4 = (const i32x4*)er;
  const u32x4* cv4 = (const u32x4*)cvps;
  for (int i = g * 256 + threadIdx.x; i < nv; i += ngrp * 256) {
    i32x4 r = __builtin_nontemporal_load(&er4[i]);
    u32x4 p = __builtin_nontemporal_load(&cv4[i]);
    if (((r.x >> 9) & 7) == s) cvp[atomicAdd(&cursor[r.x], 1)] = p.x;
    if (((r.y >> 9) & 7) == s) cvp[atomicAdd(&cursor[r.y], 1)] = p.y;
    if (((r.z >> 9) & 7) == s) cvp[atomicAdd(&cursor[r.z], 1)] = p.z;
    if (((r.w >> 9) & 7) == s) cvp[atomicAdd(&cursor[r.w], 1)] = p.w;
  }
  int tail = nv << 2;
  if (blockIdx.x == 0 && threadIdx.x < E - tail) {
    int i = tail + threadIdx.x;
    cvp[atomicAdd(&cursor[er[i]], 1)] = cvps[i];
  }
}

// ---------------------------------------------------------------------------
// SPMM1 (CSR, F=256, fp8 X -> bf16 Y, fused ReLU): wave per row, 4 edges per
// step (16-lane groups), 16 feats x 16 B gather per lane, HW fp8 decode.
// ---------------------------------------------------------------------------
__global__ __launch_bounds__(256) void spmm_fp8(
    const int* __restrict__ row_ptr, const unsigned int* __restrict__ cvp,
    const unsigned char* __restrict__ X, unsigned short* __restrict__ Y, int M) {
  int wave = (blockIdx.x * 256 + threadIdx.x) >> 6;
  int lane = threadIdx.x & 63;
  if (wave >= M) return;
  int start = row_ptr[wave], end = row_ptr[wave + 1];
  int qf = lane >> 4, fl = lane & 15;
  f32x4 a0 = (f32x4)0.f, a1 = (f32x4)0.f, a2 = (f32x4)0.f, a3 = (f32x4)0.f;
  const unsigned char* Xf = X + fl * 16;
#pragma unroll 2
  for (int e = start; e < end; e += 4) {
    int ei = e + qf;
    unsigned int p = (ei < end) ? cvp[ei] : 0u;
    float val = decode_val(p);
    size_t col = (size_t)(p >> 15);
    u32x4 d = *(const u32x4*)(Xf + col * N_HID);
    f32x2 f0 = __builtin_amdgcn_cvt_pk_f32_fp8(d.x, false);
    f32x2 f1 = __builtin_amdgcn_cvt_pk_f32_fp8(d.x, true);
    f32x2 f2 = __builtin_amdgcn_cvt_pk_f32_fp8(d.y, false);
    f32x2 f3 = __builtin_amdgcn_cvt_pk_f32_fp8(d.y, true);
    f32x2 f4 = __builtin_amdgcn_cvt_pk_f32_fp8(d.z, false);
    f32x2 f5 = __builtin_amdgcn_cvt_pk_f32_fp8(d.z, true);
    f32x2 f6 = __builtin_amdgcn_cvt_pk_f32_fp8(d.w, false);
    f32x2 f7 = __builtin_amdgcn_cvt_pk_f32_fp8(d.w, true);
    a0.x = fmaf(val, f0.x, a0.x); a0.y = fmaf(val, f0.y, a0.y);
    a0.z = fmaf(val, f1.x, a0.z); a0.w = fmaf(val, f1.y, a0.w);
    a1.x = fmaf(val, f2.x, a1.x); a1.y = fmaf(val, f2.y, a1.y);
    a1.z = fmaf(val, f3.x, a1.z); a1.w = fmaf(val, f3.y, a1.w);
    a2.x = fmaf(val, f4.x, a2.x); a2.y = fmaf(val, f4.y, a2.y);
    a2.z = fmaf(val, f5.x, a2.z); a2.w = fmaf(val, f5.y, a2.w);
    a3.x = fmaf(val, f6.x, a3.x); a3.y = fmaf(val, f6.y, a3.y);
    a3.z = fmaf(val, f7.x, a3.z); a3.w = fmaf(val, f7.y, a3.w);
  }
#define RED2(v) v += __shfl_xor(v, 16); v += __shfl_xor(v, 32);
  RED2(a0.x) RED2(a0.y) RED2(a0.z) RED2(a0.w)
  RED2(a1.x) RED2(a1.y) RED2(a1.z) RED2(a1.w)
  RED2(a2.x) RED2(a2.y) RED2(a2.z) RED2(a2.w)
  RED2(a3.x) RED2(a3.y) RED2(a3.z) RED2(a3.w)
#undef RED2
  if (qf == 0) {
    u16x8 o;
    o[0] = f2bu(fmaxf(a0.x, 0.f)); o[1] = f2bu(fmaxf(a0.y, 0.f));
    o[2] = f2bu(fmaxf(a0.z, 0.f)); o[3] = f2bu(fmaxf(a0.w, 0.f));
    o[4] = f2bu(fmaxf(a1.x, 0.f)); o[5] = f2bu(fmaxf(a1.y, 0.f));
    o[6] = f2bu(fmaxf(a1.z, 0.f)); o[7] = f2bu(fmaxf(a1.w, 0.f));
    *(u16x8*)(Y + (size_t)wave * N_HID + fl * 16) = o;
    o[0] = f2bu(fmaxf(a2.x, 0.f)); o[1] = f2bu(fmaxf(a2.y, 0.f));
    o[2] = f2bu(fmaxf(a2.z, 0.f)); o[3] = f2bu(fmaxf(a2.w, 0.f));
    o[4] = f2bu(fmaxf(a3.x, 0.f)); o[5] = f2bu(fmaxf(a3.y, 0.f));
    o[6] = f2bu(fmaxf(a3.z, 0.f)); o[7] = f2bu(fmaxf(a3.w, 0.f));
    *(u16x8*)(Y + (size_t)wave * N_HID + fl * 16 + 8) = o;
  }
}

// ---------------------------------------------------------------------------
// GEMM2: O[M,40](bf16) = Hpost[M,256](bf16) @ W2[256,40] + b2; 2 rows/thread.
// ---------------------------------------------------------------------------
__global__ __launch_bounds__(256) void gemm2_kernel(
    const unsigned short* __restrict__ H, const float* __restrict__ W2,
    const float* __restrict__ b2, unsigned short* __restrict__ O, int M) {
  __shared__ float Ws[N_HID * N_CLASS];
  __shared__ float sb2[N_CLASS];
  int tid = threadIdx.x;
  for (int i = tid; i < N_HID * N_CLASS; i += 256) Ws[i] = W2[i];
  if (tid < N_CLASS) sb2[tid] = b2[tid];
  __syncthreads();
  int r0 = (blockIdx.x * 256 + tid) * 2;
  if (r0 >= M) return;
  int r1 = r0 + 1;
  bool has1 = r1 < M;
  float acc0[N_CLASS], acc1[N_CLASS];
#pragma unroll
  for (int n = 0; n < N_CLASS; n++) { acc0[n] = sb2[n]; acc1[n] = sb2[n]; }
  const unsigned short* h0 = H + (size_t)r0 * N_HID;
  const unsigned short* h1 = H + (size_t)(has1 ? r1 : r0) * N_HID;
  for (int k0 = 0; k0 < N_HID; k0 += 8) {
    u16x8 va = *(const u16x8*)(h0 + k0);
    u16x8 vb = *(const u16x8*)(h1 + k0);
#pragma unroll
    for (int j = 0; j < 8; j++) {
      float a0 = b2f(va[j]), a1 = b2f(vb[j]);
      const float* wrow = &Ws[(k0 + j) * N_CLASS];
#pragma unroll
      for (int n = 0; n < N_CLASS; n++) {
        float wv = wrow[n];
        acc0[n] = fmaf(a0, wv, acc0[n]);
        acc1[n] = fmaf(a1, wv, acc1[n]);
      }
    }
  }
  unsigned short* o0 = O + (size_t)r0 * N_CLASS;
#pragma unroll
  for (int n = 0; n < N_CLASS; n += 4) {
    ushort4 p;
    p.x = f2bu(acc0[n]); p.y = f2bu(acc0[n + 1]);
    p.z = f2bu(acc0[n + 2]); p.w = f2bu(acc0[n + 3]);
    *(ushort4*)(o0 + n) = p;
  }
  if (has1) {
    unsigned short* o1 = O + (size_t)r1 * N_CLASS;
#pragma unroll
    for (int n = 0; n < N_CLASS; n += 4) {
      ushort4 p;
      p.x = f2bu(acc1[n]); p.y = f2bu(acc1[n + 1]);
      p.z = f2bu(acc1[n + 2]); p.w = f2bu(acc1[n + 3]);
      *(ushort4*)(o1 + n) = p;
    }
  }
}

// ---------------------------------------------------------------------------
// SPMM2 (F=40, bf16 X, packed cvp) + fused log_softmax: wave/row, unroll 4
// ---------------------------------------------------------------------------
__global__ __launch_bounds__(256) void spmm_csr_40_lsm(
    const int* __restrict__ row_ptr, const unsigned int* __restrict__ cvp,
    const unsigned short* __restrict__ X, float* __restrict__ Out, int M) {
  int wave = (blockIdx.x * 256 + threadIdx.x) >> 6;
  int lane = threadIdx.x & 63;
  if (wave >= M) return;
  int start = row_ptr[wave], end = row_ptr[wave + 1];
  bool act = lane < N_CLASS;
  int ln = act ? lane : 0;
  const unsigned short* Xc = X + ln;
  float acc = 0.f;
  int e = start;
  for (; e + 4 <= end; e += 4) {
    unsigned int p0 = cvp[e], p1 = cvp[e + 1], p2 = cvp[e + 2], p3 = cvp[e + 3];
    unsigned short x0 = Xc[(size_t)(p0 >> 15) * N_CLASS];
    unsigned short x1 = Xc[(size_t)(p1 >> 15) * N_CLASS];
    unsigned short x2 = Xc[(size_t)(p2 >> 15) * N_CLASS];
    unsigned short x3 = Xc[(size_t)(p3 >> 15) * N_CLASS];
    acc = fmaf(decode_val(p0), b2f(x0), acc);
    acc = fmaf(decode_val(p1), b2f(x1), acc);
    acc = fmaf(decode_val(p2), b2f(x2), acc);
    acc = fmaf(decode_val(p3), b2f(x3), acc);
  }
  for (; e < end; e++) {
    unsigned int p0 = cvp[e];
    acc = fmaf(decode_val(p0), b2f(Xc[(size_t)(p0 >> 15) * N_CLASS]), acc);
  }
  float mv = act ? acc : -INFINITY;
#pragma unroll
  for (int off = 32; off; off >>= 1) mv = fmaxf(mv, __shfl_xor(mv, off));
  float ex = act ? expf(acc - mv) : 0.f;
  float s = ex;
#pragma unroll
  for (int off = 32; off; off >>= 1) s += __shfl_xor(s, off);
  float lse = mv + logf(s);
  if (act) Out[(size_t)wave * N_CLASS + lane] = acc - lse;
}

// ---------------------------------------------------------------------------
extern "C" void kernel_launch(void* const* d_in, const int* in_sizes, int n_in,
                              void* d_out, int out_size, void* d_ws, size_t ws_size,
                              hipStream_t stream) {
  const float* feat = (const float*)d_in[0];
  const int* er     = (const int*)d_in[1];
  const int* ec     = (const int*)d_in[2];
  const float* ev   = (const float*)d_in[3];
  const float* W1   = (const float*)d_in[4];
  const float* b1   = (const float*)d_in[5];
  const float* W2   = (const float*)d_in[6];
  const float* b2   = (const float*)d_in[7];
  float* out = (float*)d_out;
  const int M = N_NODES;
  const int E = in_sizes[1];

  char* ws = (char*)d_ws;
  unsigned char* h      = (unsigned char*)(ws);                  // 25.6 MB fp8
  unsigned short* hpost = (unsigned short*)(ws + 25600000);      // 51.2 MB bf16
  unsigned short* o     = (unsigned short*)(ws + 76800000);      // 8 MB bf16
  int* row_ptr          = (int*)(ws + 84800000);                 // 400,004 B
  int* cursor           = (int*)(ws + 85200016);                 // 400,000 B
  int* bsum             = (int*)(ws + 85600016);                 // 512 B
  unsigned int* cvp     = (unsigned int*)(ws + 85600528);        // 12.8 MB
  unsigned int* cvps    = (unsigned int*)(ws + 98400528);        // 12.8 MB
  unsigned short* W1Tsw = (unsigned short*)(ws + 111200528);     // 256 KB

  const int NB1 = (M + 1023) / 1024;  // 98

  (void)hipMemsetAsync(cursor, 0, (size_t)M * sizeof(int), stream);
  prep_kernel<<<1024, 256, 0, stream>>>(W1, W1Tsw, er, ec, ev, cursor, cvps, E);
  scan1_kernel<<<NB1, 1024, 0, stream>>>(cursor, bsum, M);
  scan2_kernel<<<1, 64, 0, stream>>>(bsum, row_ptr, NB1, M);
  scan3_kernel<<<(M + 255) / 256, 256, 0, stream>>>(cursor, bsum, row_ptr, M);
  scatter_kernel<<<2048, 256, 0, stream>>>(er, cvps, cursor, cvp, E);
  gemm1_mfma<<<(M + 63) / 64, 256, 0, stream>>>(feat, W1Tsw, b1, h, M);
  spmm_fp8<<<(M + 3) / 4, 256, 0, stream>>>(row_ptr, cvp, h, hpost, M);
  gemm2_kernel<<<(M + 511) / 512, 256, 0, stream>>>(hpost, W2, b2, o, M);
  spmm_csr_40_lsm<<<(M + 3) / 4, 256, 0, stream>>>(row_ptr, cvp, o, out, M);
}

// Round 12
// 650.220 us; speedup vs baseline: 2.7699x; 1.0273x over previous
//
#include <hip/hip_runtime.h>
#include <hip/hip_bf16.h>
#include <math.h>

#define N_NODES 100000
#define N_FEAT 500
#define N_HID 256
#define N_CLASS 40

typedef float f32x4 __attribute__((ext_vector_type(4)));
typedef float f32x2 __attribute__((ext_vector_type(2)));
typedef int i32x4 __attribute__((ext_vector_type(4)));
typedef unsigned int u32x4 __attribute__((ext_vector_type(4)));
typedef short short8 __attribute__((ext_vector_type(8)));
typedef unsigned short u16x8 __attribute__((ext_vector_type(8)));

__device__ __forceinline__ float b2f(unsigned short u) {
  union { unsigned int i; float f; } c; c.i = ((unsigned int)u) << 16; return c.f;
}
__device__ __forceinline__ unsigned short f2bu(float x) {
  __hip_bfloat16 b = __float2bfloat16(x);
  union { __hip_bfloat16 b; unsigned short u; } c; c.b = b; return c.u;
}
__device__ __forceinline__ float decode_val(unsigned int p) {
  union { unsigned int i; float f; } c; c.i = (p & 0x7FFFu) << 17; return c.f;
}
__device__ __forceinline__ unsigned char f2fp8(float x) {
  return (unsigned char)(__builtin_amdgcn_cvt_pk_fp8_f32(x, x, 0, false) & 0xFF);
}
__device__ __forceinline__ void gload_lds16(const void* gptr, void* lptr) {
  __builtin_amdgcn_global_load_lds(
      (const __attribute__((address_space(1))) unsigned int*)gptr,
      (__attribute__((address_space(3))) unsigned int*)lptr, 16, 0, 0);
}

// ---------------------------------------------------------------------------
// prep (round-9 exact): blocks 0..63 cast W1 -> W1Tsw bf16 swizzled; all
// blocks: histogram of er + pack cvps[i] = col<<15 | bf16(val)>>1, edge order.
// ---------------------------------------------------------------------------
__global__ __launch_bounds__(256) void prep_kernel(
    const float* __restrict__ W1, unsigned short* __restrict__ Bsw,
    const int* __restrict__ er, const int* __restrict__ ec,
    const float* __restrict__ ev, int* __restrict__ cnt,
    unsigned int* __restrict__ cvps, int E) {
  if (blockIdx.x < 64) {
    int t = blockIdx.x * 256 + threadIdx.x;
    int col = t >> 6, ch = t & 63;
    int g = ch >> 3, c = ch & 7;
    int c_src = c ^ (col & 7);
    int k = g * 64 + c_src * 8;
    u16x8 o;
#pragma unroll
    for (int j = 0; j < 8; j++) {
      int kk = k + j;
      o[j] = (kk < N_FEAT) ? f2bu(W1[(size_t)kk * N_HID + col]) : (unsigned short)0;
    }
    *(u16x8*)(Bsw + (size_t)col * 512 + g * 64 + c * 8) = o;
  }
  int nv = E >> 2;
  int t = blockIdx.x * 256 + threadIdx.x;
  int nthr = gridDim.x * 256;
  const i32x4* er4 = (const i32x4*)er;
  const i32x4* ec4 = (const i32x4*)ec;
  const f32x4* ev4 = (const f32x4*)ev;
  for (int i = t; i < nv; i += nthr) {
    i32x4 r = __builtin_nontemporal_load(&er4[i]);
    i32x4 c = __builtin_nontemporal_load(&ec4[i]);
    f32x4 v = __builtin_nontemporal_load(&ev4[i]);
    atomicAdd(&cnt[r.x], 1);
    atomicAdd(&cnt[r.y], 1);
    atomicAdd(&cnt[r.z], 1);
    atomicAdd(&cnt[r.w], 1);
    u32x4 pk;
    pk.x = ((unsigned int)c.x << 15) | ((unsigned int)f2bu(v.x) >> 1);
    pk.y = ((unsigned int)c.y << 15) | ((unsigned int)f2bu(v.y) >> 1);
    pk.z = ((unsigned int)c.z << 15) | ((unsigned int)f2bu(v.z) >> 1);
    pk.w = ((unsigned int)c.w << 15) | ((unsigned int)f2bu(v.w) >> 1);
    __builtin_nontemporal_store(pk, (u32x4*)(cvps + 4 * (size_t)i));
  }
  int tail = nv << 2;
  if (blockIdx.x == 0 && threadIdx.x < E - tail) {
    int i = tail + threadIdx.x;
    atomicAdd(&cnt[er[i]], 1);
    cvps[i] = ((unsigned int)ec[i] << 15) | ((unsigned int)f2bu(ev[i]) >> 1);
  }
}

// ---------------------------------------------------------------------------
// GEMM1 (bf16 MFMA): H[M,256] = A[M,500] @ W1 + b1, fp8-e4m3 out.
// BM=32 (was 64): grid 3125, 36 KB LDS -> more resident blocks, shorter
// serial chain. Structure otherwise round-9 exact.
// ---------------------------------------------------------------------------
__global__ __launch_bounds__(256) void gemm1_mfma(
    const float* __restrict__ A, const unsigned short* __restrict__ Bsw,
    const float* __restrict__ b1, unsigned char* __restrict__ H, int M) {
  __shared__ __align__(16) char smem[36864];
  char* sA = smem;            // [32 rows][128 B]
  char* sB = smem + 4096;     // [256 cols][128 B]
  int tid = threadIdx.x;
  int lane = tid & 63, w = tid >> 6;
  int wc = w;
  int bm = blockIdx.x * 32;

  f32x4 acc[2][4];
#pragma unroll
  for (int m = 0; m < 2; m++)
#pragma unroll
    for (int n = 0; n < 4; n++) acc[m][n] = (f32x4)0.f;

  for (int s = 0; s < 8; s++) {
    int k0 = s * 64;
    // stage A: 32 rows x 16 float4 = 512 / 256 thr = 2 each
#pragma unroll
    for (int i = 0; i < 2; i++) {
      int f4 = i * 256 + tid;
      int row = f4 >> 4, cidx = f4 & 15;
      int grow = bm + row;
      int k = k0 + cidx * 4;
      float4 v = make_float4(0.f, 0.f, 0.f, 0.f);
      if (grow < M && k < N_FEAT) v = *(const float4*)(A + (size_t)grow * N_FEAT + k);
      ushort4 u;
      u.x = f2bu(v.x); u.y = f2bu(v.y); u.z = f2bu(v.z); u.w = f2bu(v.w);
      int chunk = cidx >> 1, sub = cidx & 1;
      int byte = row * 128 + (((chunk ^ (row & 7))) << 4) + (sub << 3);
      *(ushort4*)(sA + byte) = u;
    }
    // stage B: 32 KB / (256 thr * 16 B) = 8 gload_lds each (linear dest)
#pragma unroll
    for (int j = 0; j < 8; j++) {
      int base = j * 4096 + w * 1024;
      int L = base + lane * 16;
      int col = L >> 7, c = (L >> 4) & 7;
      const char* g = (const char*)Bsw + (size_t)col * 1024 + s * 128 + c * 16;
      gload_lds16(g, sB + base);
    }
    __syncthreads();
#pragma unroll
    for (int kk = 0; kk < 2; kk++) {
      int cw = kk * 4 + (lane >> 4);
      short8 af[2], bg[4];
#pragma unroll
      for (int m = 0; m < 2; m++) {
        int ar = m * 16 + (lane & 15);
        af[m] = *(const short8*)(sA + ar * 128 + ((cw ^ (ar & 7)) << 4));
      }
#pragma unroll
      for (int n = 0; n < 4; n++) {
        int bc = wc * 64 + n * 16 + (lane & 15);
        bg[n] = *(const short8*)(sB + bc * 128 + ((cw ^ (bc & 7)) << 4));
      }
#pragma unroll
      for (int m = 0; m < 2; m++)
#pragma unroll
        for (int n = 0; n < 4; n++)
          acc[m][n] = __builtin_amdgcn_mfma_f32_16x16x32_bf16(af[m], bg[n], acc[m][n], 0, 0, 0);
    }
    __syncthreads();
  }

  float bias[4];
#pragma unroll
  for (int n = 0; n < 4; n++) bias[n] = b1[wc * 64 + n * 16 + (lane & 15)];
#pragma unroll
  for (int m = 0; m < 2; m++) {
#pragma unroll
    for (int r = 0; r < 4; r++) {
      int row = bm + m * 16 + ((lane >> 4) << 2) + r;
      if (row < M) {
#pragma unroll
        for (int n = 0; n < 4; n++) {
          int col = wc * 64 + n * 16 + (lane & 15);
          H[(size_t)row * N_HID + col] = f2fp8(acc[m][n][r] + bias[n]);
        }
      }
    }
  }
}

// ---------------------------------------------------------------------------
// scans (unchanged)
// ---------------------------------------------------------------------------
__global__ __launch_bounds__(1024) void scan1_kernel(
    int* __restrict__ cnt, int* __restrict__ bsum, int n) {
  __shared__ int wsum[16];
  int tid = threadIdx.x, lane = tid & 63, wid = tid >> 6;
  int i = blockIdx.x * 1024 + tid;
  int v = (i < n) ? cnt[i] : 0;
  int x = v;
#pragma unroll
  for (int off = 1; off < 64; off <<= 1) {
    int t = __shfl_up(x, off);
    if (lane >= off) x += t;
  }
  if (lane == 63) wsum[wid] = x;
  __syncthreads();
  if (tid < 16) {
    int ws = wsum[tid];
#pragma unroll
    for (int off = 1; off < 16; off <<= 1) {
      int t = __shfl_up(ws, off);
      if (tid >= off) ws += t;
    }
    wsum[tid] = ws;
  }
  __syncthreads();
  int excl = (wid ? wsum[wid - 1] : 0) + x - v;
  if (i < n) cnt[i] = excl;
  if (tid == 0) bsum[blockIdx.x] = wsum[15];
}

__global__ __launch_bounds__(64) void scan2_kernel(
    int* __restrict__ bsum, int* __restrict__ row_ptr, int nb, int n) {
  int lane = threadIdx.x;
  int carry = 0;
  for (int base = 0; base < nb; base += 64) {
    int i = base + lane;
    int v = (i < nb) ? bsum[i] : 0;
    int x = v;
#pragma unroll
    for (int off = 1; off < 64; off <<= 1) {
      int t = __shfl_up(x, off);
      if (lane >= off) x += t;
    }
    if (i < nb) bsum[i] = carry + x - v;
    carry += __shfl(x, 63);
  }
  if (lane == 0) row_ptr[n] = carry;
}

__global__ __launch_bounds__(256) void scan3_kernel(
    int* __restrict__ cnt, const int* __restrict__ bsum,
    int* __restrict__ row_ptr, int n) {
  int i = blockIdx.x * 256 + threadIdx.x;
  if (i >= n) return;
  int v = cnt[i] + bsum[i >> 10];
  cnt[i] = v;
  row_ptr[i] = v;
}

// ---------------------------------------------------------------------------
// XCD-sliced scatter, 4 slices (was 8): block b handles slice (row>>9)&3 ==
// b&3. Scan volume halves (4x re-read of er+cvps, L3-resident); cvp/cursor
// lines shared by 2 XCDs (acceptable churn per round-4/6 evidence).
// ---------------------------------------------------------------------------
__global__ __launch_bounds__(256) void scatter_kernel(
    const int* __restrict__ er, const unsigned int* __restrict__ cvps,
    int* __restrict__ cursor, unsigned int* __restrict__ cvp, int E) {
  int s = blockIdx.x & 3;
  int g = blockIdx.x >> 2;
  int ngrp = gridDim.x >> 2;
  int nv = E >> 2;
  const i32x4* er4 = (const i32x4*)er;
  const u32x4* cv4 = (const u32x4*)cvps;
  for (int i = g * 256 + threadIdx.x; i < nv; i += ngrp * 256) {
    i32x4 r = __builtin_nontemporal_load(&er4[i]);
    u32x4 p = __builtin_nontemporal_load(&cv4[i]);
    if (((r.x >> 9) & 3) == s) cvp[atomicAdd(&cursor[r.x], 1)] = p.x;
    if (((r.y >> 9) & 3) == s) cvp[atomicAdd(&cursor[r.y], 1)] = p.y;
    if (((r.z >> 9) & 3) == s) cvp[atomicAdd(&cursor[r.z], 1)] = p.z;
    if (((r.w >> 9) & 3) == s) cvp[atomicAdd(&cursor[r.w], 1)] = p.w;
  }
  int tail = nv << 2;
  if (blockIdx.x == 0 && threadIdx.x < E - tail) {
    int i = tail + threadIdx.x;
    cvp[atomicAdd(&cursor[er[i]], 1)] = cvps[i];
  }
}

// ---------------------------------------------------------------------------
// SPMM1 (CSR, F=256, fp8 X -> bf16 Y, fused ReLU): wave per row, 4 edges per
// step (16-lane groups), 16 feats x 16 B gather per lane, HW fp8 decode.
// ---------------------------------------------------------------------------
__global__ __launch_bounds__(256) void spmm_fp8(
    const int* __restrict__ row_ptr, const unsigned int* __restrict__ cvp,
    const unsigned char* __restrict__ X, unsigned short* __restrict__ Y, int M) {
  int wave = (blockIdx.x * 256 + threadIdx.x) >> 6;
  int lane = threadIdx.x & 63;
  if (wave >= M) return;
  int start = row_ptr[wave], end = row_ptr[wave + 1];
  int qf = lane >> 4, fl = lane & 15;
  f32x4 a0 = (f32x4)0.f, a1 = (f32x4)0.f, a2 = (f32x4)0.f, a3 = (f32x4)0.f;
  const unsigned char* Xf = X + fl * 16;
#pragma unroll 2
  for (int e = start; e < end; e += 4) {
    int ei = e + qf;
    unsigned int p = (ei < end) ? cvp[ei] : 0u;
    float val = decode_val(p);
    size_t col = (size_t)(p >> 15);
    u32x4 d = *(const u32x4*)(Xf + col * N_HID);
    f32x2 f0 = __builtin_amdgcn_cvt_pk_f32_fp8(d.x, false);
    f32x2 f1 = __builtin_amdgcn_cvt_pk_f32_fp8(d.x, true);
    f32x2 f2 = __builtin_amdgcn_cvt_pk_f32_fp8(d.y, false);
    f32x2 f3 = __builtin_amdgcn_cvt_pk_f32_fp8(d.y, true);
    f32x2 f4 = __builtin_amdgcn_cvt_pk_f32_fp8(d.z, false);
    f32x2 f5 = __builtin_amdgcn_cvt_pk_f32_fp8(d.z, true);
    f32x2 f6 = __builtin_amdgcn_cvt_pk_f32_fp8(d.w, false);
    f32x2 f7 = __builtin_amdgcn_cvt_pk_f32_fp8(d.w, true);
    a0.x = fmaf(val, f0.x, a0.x); a0.y = fmaf(val, f0.y, a0.y);
    a0.z = fmaf(val, f1.x, a0.z); a0.w = fmaf(val, f1.y, a0.w);
    a1.x = fmaf(val, f2.x, a1.x); a1.y = fmaf(val, f2.y, a1.y);
    a1.z = fmaf(val, f3.x, a1.z); a1.w = fmaf(val, f3.y, a1.w);
    a2.x = fmaf(val, f4.x, a2.x); a2.y = fmaf(val, f4.y, a2.y);
    a2.z = fmaf(val, f5.x, a2.z); a2.w = fmaf(val, f5.y, a2.w);
    a3.x = fmaf(val, f6.x, a3.x); a3.y = fmaf(val, f6.y, a3.y);
    a3.z = fmaf(val, f7.x, a3.z); a3.w = fmaf(val, f7.y, a3.w);
  }
#define RED2(v) v += __shfl_xor(v, 16); v += __shfl_xor(v, 32);
  RED2(a0.x) RED2(a0.y) RED2(a0.z) RED2(a0.w)
  RED2(a1.x) RED2(a1.y) RED2(a1.z) RED2(a1.w)
  RED2(a2.x) RED2(a2.y) RED2(a2.z) RED2(a2.w)
  RED2(a3.x) RED2(a3.y) RED2(a3.z) RED2(a3.w)
#undef RED2
  if (qf == 0) {
    u16x8 o;
    o[0] = f2bu(fmaxf(a0.x, 0.f)); o[1] = f2bu(fmaxf(a0.y, 0.f));
    o[2] = f2bu(fmaxf(a0.z, 0.f)); o[3] = f2bu(fmaxf(a0.w, 0.f));
    o[4] = f2bu(fmaxf(a1.x, 0.f)); o[5] = f2bu(fmaxf(a1.y, 0.f));
    o[6] = f2bu(fmaxf(a1.z, 0.f)); o[7] = f2bu(fmaxf(a1.w, 0.f));
    *(u16x8*)(Y + (size_t)wave * N_HID + fl * 16) = o;
    o[0] = f2bu(fmaxf(a2.x, 0.f)); o[1] = f2bu(fmaxf(a2.y, 0.f));
    o[2] = f2bu(fmaxf(a2.z, 0.f)); o[3] = f2bu(fmaxf(a2.w, 0.f));
    o[4] = f2bu(fmaxf(a3.x, 0.f)); o[5] = f2bu(fmaxf(a3.y, 0.f));
    o[6] = f2bu(fmaxf(a3.z, 0.f)); o[7] = f2bu(fmaxf(a3.w, 0.f));
    *(u16x8*)(Y + (size_t)wave * N_HID + fl * 16 + 8) = o;
  }
}

// ---------------------------------------------------------------------------
// GEMM2: O[M,40](bf16) = Hpost[M,256](bf16) @ W2[256,40] + b2; 2 rows/thread.
// ---------------------------------------------------------------------------
__global__ __launch_bounds__(256) void gemm2_kernel(
    const unsigned short* __restrict__ H, const float* __restrict__ W2,
    const float* __restrict__ b2, unsigned short* __restrict__ O, int M) {
  __shared__ float Ws[N_HID * N_CLASS];
  __shared__ float sb2[N_CLASS];
  int tid = threadIdx.x;
  for (int i = tid; i < N_HID * N_CLASS; i += 256) Ws[i] = W2[i];
  if (tid < N_CLASS) sb2[tid] = b2[tid];
  __syncthreads();
  int r0 = (blockIdx.x * 256 + tid) * 2;
  if (r0 >= M) return;
  int r1 = r0 + 1;
  bool has1 = r1 < M;
  float acc0[N_CLASS], acc1[N_CLASS];
#pragma unroll
  for (int n = 0; n < N_CLASS; n++) { acc0[n] = sb2[n]; acc1[n] = sb2[n]; }
  const unsigned short* h0 = H + (size_t)r0 * N_HID;
  const unsigned short* h1 = H + (size_t)(has1 ? r1 : r0) * N_HID;
  for (int k0 = 0; k0 < N_HID; k0 += 8) {
    u16x8 va = *(const u16x8*)(h0 + k0);
    u16x8 vb = *(const u16x8*)(h1 + k0);
#pragma unroll
    for (int j = 0; j < 8; j++) {
      float a0 = b2f(va[j]), a1 = b2f(vb[j]);
      const float* wrow = &Ws[(k0 + j) * N_CLASS];
#pragma unroll
      for (int n = 0; n < N_CLASS; n++) {
        float wv = wrow[n];
        acc0[n] = fmaf(a0, wv, acc0[n]);
        acc1[n] = fmaf(a1, wv, acc1[n]);
      }
    }
  }
  unsigned short* o0 = O + (size_t)r0 * N_CLASS;
#pragma unroll
  for (int n = 0; n < N_CLASS; n += 4) {
    ushort4 p;
    p.x = f2bu(acc0[n]); p.y = f2bu(acc0[n + 1]);
    p.z = f2bu(acc0[n + 2]); p.w = f2bu(acc0[n + 3]);
    *(ushort4*)(o0 + n) = p;
  }
  if (has1) {
    unsigned short* o1 = O + (size_t)r1 * N_CLASS;
#pragma unroll
    for (int n = 0; n < N_CLASS; n += 4) {
      ushort4 p;
      p.x = f2bu(acc1[n]); p.y = f2bu(acc1[n + 1]);
      p.z = f2bu(acc1[n + 2]); p.w = f2bu(acc1[n + 3]);
      *(ushort4*)(o1 + n) = p;
    }
  }
}

// ---------------------------------------------------------------------------
// SPMM2 (F=40, bf16 X, packed cvp) + fused log_softmax: wave/row, unroll 4
// ---------------------------------------------------------------------------
__global__ __launch_bounds__(256) void spmm_csr_40_lsm(
    const int* __restrict__ row_ptr, const unsigned int* __restrict__ cvp,
    const unsigned short* __restrict__ X, float* __restrict__ Out, int M) {
  int wave = (blockIdx.x * 256 + threadIdx.x) >> 6;
  int lane = threadIdx.x & 63;
  if (wave >= M) return;
  int start = row_ptr[wave], end = row_ptr[wave + 1];
  bool act = lane < N_CLASS;
  int ln = act ? lane : 0;
  const unsigned short* Xc = X + ln;
  float acc = 0.f;
  int e = start;
  for (; e + 4 <= end; e += 4) {
    unsigned int p0 = cvp[e], p1 = cvp[e + 1], p2 = cvp[e + 2], p3 = cvp[e + 3];
    unsigned short x0 = Xc[(size_t)(p0 >> 15) * N_CLASS];
    unsigned short x1 = Xc[(size_t)(p1 >> 15) * N_CLASS];
    unsigned short x2 = Xc[(size_t)(p2 >> 15) * N_CLASS];
    unsigned short x3 = Xc[(size_t)(p3 >> 15) * N_CLASS];
    acc = fmaf(decode_val(p0), b2f(x0), acc);
    acc = fmaf(decode_val(p1), b2f(x1), acc);
    acc = fmaf(decode_val(p2), b2f(x2), acc);
    acc = fmaf(decode_val(p3), b2f(x3), acc);
  }
  for (; e < end; e++) {
    unsigned int p0 = cvp[e];
    acc = fmaf(decode_val(p0), b2f(Xc[(size_t)(p0 >> 15) * N_CLASS]), acc);
  }
  float mv = act ? acc : -INFINITY;
#pragma unroll
  for (int off = 32; off; off >>= 1) mv = fmaxf(mv, __shfl_xor(mv, off));
  float ex = act ? expf(acc - mv) : 0.f;
  float s = ex;
#pragma unroll
  for (int off = 32; off; off >>= 1) s += __shfl_xor(s, off);
  float lse = mv + logf(s);
  if (act) Out[(size_t)wave * N_CLASS + lane] = acc - lse;
}

// ---------------------------------------------------------------------------
extern "C" void kernel_launch(void* const* d_in, const int* in_sizes, int n_in,
                              void* d_out, int out_size, void* d_ws, size_t ws_size,
                              hipStream_t stream) {
  const float* feat = (const float*)d_in[0];
  const int* er     = (const int*)d_in[1];
  const int* ec     = (const int*)d_in[2];
  const float* ev   = (const float*)d_in[3];
  const float* W1   = (const float*)d_in[4];
  const float* b1   = (const float*)d_in[5];
  const float* W2   = (const float*)d_in[6];
  const float* b2   = (const float*)d_in[7];
  float* out = (float*)d_out;
  const int M = N_NODES;
  const int E = in_sizes[1];

  char* ws = (char*)d_ws;
  unsigned char* h      = (unsigned char*)(ws);                  // 25.6 MB fp8
  unsigned short* hpost = (unsigned short*)(ws + 25600000);      // 51.2 MB bf16
  unsigned short* o     = (unsigned short*)(ws + 76800000);      // 8 MB bf16
  int* row_ptr          = (int*)(ws + 84800000);                 // 400,004 B
  int* cursor           = (int*)(ws + 85200016);                 // 400,000 B
  int* bsum             = (int*)(ws + 85600016);                 // 512 B
  unsigned int* cvp     = (unsigned int*)(ws + 85600528);        // 12.8 MB
  unsigned int* cvps    = (unsigned int*)(ws + 98400528);        // 12.8 MB
  unsigned short* W1Tsw = (unsigned short*)(ws + 111200528);     // 256 KB

  const int NB1 = (M + 1023) / 1024;  // 98

  (void)hipMemsetAsync(cursor, 0, (size_t)M * sizeof(int), stream);
  prep_kernel<<<1024, 256, 0, stream>>>(W1, W1Tsw, er, ec, ev, cursor, cvps, E);
  scan1_kernel<<<NB1, 1024, 0, stream>>>(cursor, bsum, M);
  scan2_kernel<<<1, 64, 0, stream>>>(bsum, row_ptr, NB1, M);
  scan3_kernel<<<(M + 255) / 256, 256, 0, stream>>>(cursor, bsum, row_ptr, M);
  scatter_kernel<<<2048, 256, 0, stream>>>(er, cvps, cursor, cvp, E);
  gemm1_mfma<<<(M + 31) / 32, 256, 0, stream>>>(feat, W1Tsw, b1, h, M);
  spmm_fp8<<<(M + 3) / 4, 256, 0, stream>>>(row_ptr, cvp, h, hpost, M);
  gemm2_kernel<<<(M + 511) / 512, 256, 0, stream>>>(hpost, W2, b2, o, M);
  spmm_csr_40_lsm<<<(M + 3) / 4, 256, 0, stream>>>(row_ptr, cvp, o, out, M);
}

// Round 13
// 642.348 us; speedup vs baseline: 2.8039x; 1.0123x over previous
//
#include <hip/hip_runtime.h>
#include <hip/hip_bf16.h>
#include <math.h>

#define N_NODES 100000
#define N_FEAT 500
#define N_HID 256
#define N_CLASS 40

typedef float f32x4 __attribute__((ext_vector_type(4)));
typedef float f32x2 __attribute__((ext_vector_type(2)));
typedef int i32x4 __attribute__((ext_vector_type(4)));
typedef unsigned int u32x4 __attribute__((ext_vector_type(4)));
typedef short short8 __attribute__((ext_vector_type(8)));
typedef unsigned short u16x8 __attribute__((ext_vector_type(8)));

__device__ __forceinline__ float b2f(unsigned short u) {
  union { unsigned int i; float f; } c; c.i = ((unsigned int)u) << 16; return c.f;
}
__device__ __forceinline__ unsigned short f2bu(float x) {
  __hip_bfloat16 b = __float2bfloat16(x);
  union { __hip_bfloat16 b; unsigned short u; } c; c.b = b; return c.u;
}
__device__ __forceinline__ float decode_val(unsigned int p) {
  union { unsigned int i; float f; } c; c.i = (p & 0x7FFFu) << 17; return c.f;
}
__device__ __forceinline__ unsigned char f2fp8(float x) {
  return (unsigned char)(__builtin_amdgcn_cvt_pk_fp8_f32(x, x, 0, false) & 0xFF);
}
__device__ __forceinline__ void gload_lds16(const void* gptr, void* lptr) {
  __builtin_amdgcn_global_load_lds(
      (const __attribute__((address_space(1))) unsigned int*)gptr,
      (__attribute__((address_space(3))) unsigned int*)lptr, 16, 0, 0);
}

// ---------------------------------------------------------------------------
// prep (round-9 exact): blocks 0..63 cast W1 -> W1Tsw bf16 swizzled; all
// blocks: histogram of er + pack cvps[i] = col<<15 | bf16(val)>>1, edge order.
// ---------------------------------------------------------------------------
__global__ __launch_bounds__(256) void prep_kernel(
    const float* __restrict__ W1, unsigned short* __restrict__ Bsw,
    const int* __restrict__ er, const int* __restrict__ ec,
    const float* __restrict__ ev, int* __restrict__ cnt,
    unsigned int* __restrict__ cvps, int E) {
  if (blockIdx.x < 64) {
    int t = blockIdx.x * 256 + threadIdx.x;
    int col = t >> 6, ch = t & 63;
    int g = ch >> 3, c = ch & 7;
    int c_src = c ^ (col & 7);
    int k = g * 64 + c_src * 8;
    u16x8 o;
#pragma unroll
    for (int j = 0; j < 8; j++) {
      int kk = k + j;
      o[j] = (kk < N_FEAT) ? f2bu(W1[(size_t)kk * N_HID + col]) : (unsigned short)0;
    }
    *(u16x8*)(Bsw + (size_t)col * 512 + g * 64 + c * 8) = o;
  }
  int nv = E >> 2;
  int t = blockIdx.x * 256 + threadIdx.x;
  int nthr = gridDim.x * 256;
  const i32x4* er4 = (const i32x4*)er;
  const i32x4* ec4 = (const i32x4*)ec;
  const f32x4* ev4 = (const f32x4*)ev;
  for (int i = t; i < nv; i += nthr) {
    i32x4 r = __builtin_nontemporal_load(&er4[i]);
    i32x4 c = __builtin_nontemporal_load(&ec4[i]);
    f32x4 v = __builtin_nontemporal_load(&ev4[i]);
    atomicAdd(&cnt[r.x], 1);
    atomicAdd(&cnt[r.y], 1);
    atomicAdd(&cnt[r.z], 1);
    atomicAdd(&cnt[r.w], 1);
    u32x4 pk;
    pk.x = ((unsigned int)c.x << 15) | ((unsigned int)f2bu(v.x) >> 1);
    pk.y = ((unsigned int)c.y << 15) | ((unsigned int)f2bu(v.y) >> 1);
    pk.z = ((unsigned int)c.z << 15) | ((unsigned int)f2bu(v.z) >> 1);
    pk.w = ((unsigned int)c.w << 15) | ((unsigned int)f2bu(v.w) >> 1);
    __builtin_nontemporal_store(pk, (u32x4*)(cvps + 4 * (size_t)i));
  }
  int tail = nv << 2;
  if (blockIdx.x == 0 && threadIdx.x < E - tail) {
    int i = tail + threadIdx.x;
    atomicAdd(&cnt[er[i]], 1);
    cvps[i] = ((unsigned int)ec[i] << 15) | ((unsigned int)f2bu(ev[i]) >> 1);
  }
}

// ---------------------------------------------------------------------------
// scans (unchanged)
// ---------------------------------------------------------------------------
__global__ __launch_bounds__(1024) void scan1_kernel(
    int* __restrict__ cnt, int* __restrict__ bsum, int n) {
  __shared__ int wsum[16];
  int tid = threadIdx.x, lane = tid & 63, wid = tid >> 6;
  int i = blockIdx.x * 1024 + tid;
  int v = (i < n) ? cnt[i] : 0;
  int x = v;
#pragma unroll
  for (int off = 1; off < 64; off <<= 1) {
    int t = __shfl_up(x, off);
    if (lane >= off) x += t;
  }
  if (lane == 63) wsum[wid] = x;
  __syncthreads();
  if (tid < 16) {
    int ws = wsum[tid];
#pragma unroll
    for (int off = 1; off < 16; off <<= 1) {
      int t = __shfl_up(ws, off);
      if (tid >= off) ws += t;
    }
    wsum[tid] = ws;
  }
  __syncthreads();
  int excl = (wid ? wsum[wid - 1] : 0) + x - v;
  if (i < n) cnt[i] = excl;
  if (tid == 0) bsum[blockIdx.x] = wsum[15];
}

__global__ __launch_bounds__(64) void scan2_kernel(
    int* __restrict__ bsum, int* __restrict__ row_ptr, int nb, int n) {
  int lane = threadIdx.x;
  int carry = 0;
  for (int base = 0; base < nb; base += 64) {
    int i = base + lane;
    int v = (i < nb) ? bsum[i] : 0;
    int x = v;
#pragma unroll
    for (int off = 1; off < 64; off <<= 1) {
      int t = __shfl_up(x, off);
      if (lane >= off) x += t;
    }
    if (i < nb) bsum[i] = carry + x - v;
    carry += __shfl(x, 63);
  }
  if (lane == 0) row_ptr[n] = carry;
}

__global__ __launch_bounds__(256) void scan3_kernel(
    int* __restrict__ cnt, const int* __restrict__ bsum,
    int* __restrict__ row_ptr, int n) {
  int i = blockIdx.x * 256 + threadIdx.x;
  if (i >= n) return;
  int v = cnt[i] + bsum[i >> 10];
  cnt[i] = v;
  row_ptr[i] = v;
}

// ---------------------------------------------------------------------------
// FUSED scatter + gemm1: blocks [0, SB) run the r12 4-slice scatter body;
// blocks [SB, SB+GB) run the r12 BM=32 gemm1 body. The two are
// data-independent; co-residency lets scatter's memory streams fill gemm1's
// latency bubbles. Static 36 KB LDS applies to all blocks (<=4 blk/CU).
// ---------------------------------------------------------------------------
__global__ __launch_bounds__(256) void fused_sg(
    const int* __restrict__ er, const unsigned int* __restrict__ cvps,
    int* __restrict__ cursor, unsigned int* __restrict__ cvp, int E,
    const float* __restrict__ A, const unsigned short* __restrict__ Bsw,
    const float* __restrict__ b1, unsigned char* __restrict__ H, int M,
    int SB) {
  __shared__ __align__(16) char smem[36864];
  if ((int)blockIdx.x < SB) {
    // ---- scatter body (r12 exact, grid = SB) ----
    int sb = blockIdx.x;
    int s = sb & 3;
    int g = sb >> 2;
    int ngrp = SB >> 2;
    int nv = E >> 2;
    const i32x4* er4 = (const i32x4*)er;
    const u32x4* cv4 = (const u32x4*)cvps;
    for (int i = g * 256 + threadIdx.x; i < nv; i += ngrp * 256) {
      i32x4 r = __builtin_nontemporal_load(&er4[i]);
      u32x4 p = __builtin_nontemporal_load(&cv4[i]);
      if (((r.x >> 9) & 3) == s) cvp[atomicAdd(&cursor[r.x], 1)] = p.x;
      if (((r.y >> 9) & 3) == s) cvp[atomicAdd(&cursor[r.y], 1)] = p.y;
      if (((r.z >> 9) & 3) == s) cvp[atomicAdd(&cursor[r.z], 1)] = p.z;
      if (((r.w >> 9) & 3) == s) cvp[atomicAdd(&cursor[r.w], 1)] = p.w;
    }
    int tail = nv << 2;
    if (sb == 0 && threadIdx.x < E - tail) {
      int i = tail + threadIdx.x;
      cvp[atomicAdd(&cursor[er[i]], 1)] = cvps[i];
    }
    return;
  }
  // ---- gemm1 body (r12 exact, BM=32) ----
  int gb = blockIdx.x - SB;
  char* sA = smem;            // [32 rows][128 B]
  char* sB = smem + 4096;     // [256 cols][128 B]
  int tid = threadIdx.x;
  int lane = tid & 63, w = tid >> 6;
  int wc = w;
  int bm = gb * 32;

  f32x4 acc[2][4];
#pragma unroll
  for (int m = 0; m < 2; m++)
#pragma unroll
    for (int n = 0; n < 4; n++) acc[m][n] = (f32x4)0.f;

  for (int s = 0; s < 8; s++) {
    int k0 = s * 64;
#pragma unroll
    for (int i = 0; i < 2; i++) {
      int f4 = i * 256 + tid;
      int row = f4 >> 4, cidx = f4 & 15;
      int grow = bm + row;
      int k = k0 + cidx * 4;
      float4 v = make_float4(0.f, 0.f, 0.f, 0.f);
      if (grow < M && k < N_FEAT) v = *(const float4*)(A + (size_t)grow * N_FEAT + k);
      ushort4 u;
      u.x = f2bu(v.x); u.y = f2bu(v.y); u.z = f2bu(v.z); u.w = f2bu(v.w);
      int chunk = cidx >> 1, sub = cidx & 1;
      int byte = row * 128 + (((chunk ^ (row & 7))) << 4) + (sub << 3);
      *(ushort4*)(sA + byte) = u;
    }
#pragma unroll
    for (int j = 0; j < 8; j++) {
      int base = j * 4096 + w * 1024;
      int L = base + lane * 16;
      int col = L >> 7, c = (L >> 4) & 7;
      const char* gp = (const char*)Bsw + (size_t)col * 1024 + s * 128 + c * 16;
      gload_lds16(gp, sB + base);
    }
    __syncthreads();
#pragma unroll
    for (int kk = 0; kk < 2; kk++) {
      int cw = kk * 4 + (lane >> 4);
      short8 af[2], bg[4];
#pragma unroll
      for (int m = 0; m < 2; m++) {
        int ar = m * 16 + (lane & 15);
        af[m] = *(const short8*)(sA + ar * 128 + ((cw ^ (ar & 7)) << 4));
      }
#pragma unroll
      for (int n = 0; n < 4; n++) {
        int bc = wc * 64 + n * 16 + (lane & 15);
        bg[n] = *(const short8*)(sB + bc * 128 + ((cw ^ (bc & 7)) << 4));
      }
#pragma unroll
      for (int m = 0; m < 2; m++)
#pragma unroll
        for (int n = 0; n < 4; n++)
          acc[m][n] = __builtin_amdgcn_mfma_f32_16x16x32_bf16(af[m], bg[n], acc[m][n], 0, 0, 0);
    }
    __syncthreads();
  }

  float bias[4];
#pragma unroll
  for (int n = 0; n < 4; n++) bias[n] = b1[wc * 64 + n * 16 + (lane & 15)];
#pragma unroll
  for (int m = 0; m < 2; m++) {
#pragma unroll
    for (int r = 0; r < 4; r++) {
      int row = bm + m * 16 + ((lane >> 4) << 2) + r;
      if (row < M) {
#pragma unroll
        for (int n = 0; n < 4; n++) {
          int col = wc * 64 + n * 16 + (lane & 15);
          H[(size_t)row * N_HID + col] = f2fp8(acc[m][n][r] + bias[n]);
        }
      }
    }
  }
}

// ---------------------------------------------------------------------------
// SPMM1 (CSR, F=256, fp8 X -> bf16 Y, fused ReLU): wave per row, 4 edges per
// step (16-lane groups), 16 feats x 16 B gather per lane, HW fp8 decode.
// ---------------------------------------------------------------------------
__global__ __launch_bounds__(256) void spmm_fp8(
    const int* __restrict__ row_ptr, const unsigned int* __restrict__ cvp,
    const unsigned char* __restrict__ X, unsigned short* __restrict__ Y, int M) {
  int wave = (blockIdx.x * 256 + threadIdx.x) >> 6;
  int lane = threadIdx.x & 63;
  if (wave >= M) return;
  int start = row_ptr[wave], end = row_ptr[wave + 1];
  int qf = lane >> 4, fl = lane & 15;
  f32x4 a0 = (f32x4)0.f, a1 = (f32x4)0.f, a2 = (f32x4)0.f, a3 = (f32x4)0.f;
  const unsigned char* Xf = X + fl * 16;
#pragma unroll 2
  for (int e = start; e < end; e += 4) {
    int ei = e + qf;
    unsigned int p = (ei < end) ? cvp[ei] : 0u;
    float val = decode_val(p);
    size_t col = (size_t)(p >> 15);
    u32x4 d = *(const u32x4*)(Xf + col * N_HID);
    f32x2 f0 = __builtin_amdgcn_cvt_pk_f32_fp8(d.x, false);
    f32x2 f1 = __builtin_amdgcn_cvt_pk_f32_fp8(d.x, true);
    f32x2 f2 = __builtin_amdgcn_cvt_pk_f32_fp8(d.y, false);
    f32x2 f3 = __builtin_amdgcn_cvt_pk_f32_fp8(d.y, true);
    f32x2 f4 = __builtin_amdgcn_cvt_pk_f32_fp8(d.z, false);
    f32x2 f5 = __builtin_amdgcn_cvt_pk_f32_fp8(d.z, true);
    f32x2 f6 = __builtin_amdgcn_cvt_pk_f32_fp8(d.w, false);
    f32x2 f7 = __builtin_amdgcn_cvt_pk_f32_fp8(d.w, true);
    a0.x = fmaf(val, f0.x, a0.x); a0.y = fmaf(val, f0.y, a0.y);
    a0.z = fmaf(val, f1.x, a0.z); a0.w = fmaf(val, f1.y, a0.w);
    a1.x = fmaf(val, f2.x, a1.x); a1.y = fmaf(val, f2.y, a1.y);
    a1.z = fmaf(val, f3.x, a1.z); a1.w = fmaf(val, f3.y, a1.w);
    a2.x = fmaf(val, f4.x, a2.x); a2.y = fmaf(val, f4.y, a2.y);
    a2.z = fmaf(val, f5.x, a2.z); a2.w = fmaf(val, f5.y, a2.w);
    a3.x = fmaf(val, f6.x, a3.x); a3.y = fmaf(val, f6.y, a3.y);
    a3.z = fmaf(val, f7.x, a3.z); a3.w = fmaf(val, f7.y, a3.w);
  }
#define RED2(v) v += __shfl_xor(v, 16); v += __shfl_xor(v, 32);
  RED2(a0.x) RED2(a0.y) RED2(a0.z) RED2(a0.w)
  RED2(a1.x) RED2(a1.y) RED2(a1.z) RED2(a1.w)
  RED2(a2.x) RED2(a2.y) RED2(a2.z) RED2(a2.w)
  RED2(a3.x) RED2(a3.y) RED2(a3.z) RED2(a3.w)
#undef RED2
  if (qf == 0) {
    u16x8 o;
    o[0] = f2bu(fmaxf(a0.x, 0.f)); o[1] = f2bu(fmaxf(a0.y, 0.f));
    o[2] = f2bu(fmaxf(a0.z, 0.f)); o[3] = f2bu(fmaxf(a0.w, 0.f));
    o[4] = f2bu(fmaxf(a1.x, 0.f)); o[5] = f2bu(fmaxf(a1.y, 0.f));
    o[6] = f2bu(fmaxf(a1.z, 0.f)); o[7] = f2bu(fmaxf(a1.w, 0.f));
    *(u16x8*)(Y + (size_t)wave * N_HID + fl * 16) = o;
    o[0] = f2bu(fmaxf(a2.x, 0.f)); o[1] = f2bu(fmaxf(a2.y, 0.f));
    o[2] = f2bu(fmaxf(a2.z, 0.f)); o[3] = f2bu(fmaxf(a2.w, 0.f));
    o[4] = f2bu(fmaxf(a3.x, 0.f)); o[5] = f2bu(fmaxf(a3.y, 0.f));
    o[6] = f2bu(fmaxf(a3.z, 0.f)); o[7] = f2bu(fmaxf(a3.w, 0.f));
    *(u16x8*)(Y + (size_t)wave * N_HID + fl * 16 + 8) = o;
  }
}

// ---------------------------------------------------------------------------
// GEMM2: O[M,40](bf16) = Hpost[M,256](bf16) @ W2[256,40] + b2; 2 rows/thread.
// ---------------------------------------------------------------------------
__global__ __launch_bounds__(256) void gemm2_kernel(
    const unsigned short* __restrict__ H, const float* __restrict__ W2,
    const float* __restrict__ b2, unsigned short* __restrict__ O, int M) {
  __shared__ float Ws[N_HID * N_CLASS];
  __shared__ float sb2[N_CLASS];
  int tid = threadIdx.x;
  for (int i = tid; i < N_HID * N_CLASS; i += 256) Ws[i] = W2[i];
  if (tid < N_CLASS) sb2[tid] = b2[tid];
  __syncthreads();
  int r0 = (blockIdx.x * 256 + tid) * 2;
  if (r0 >= M) return;
  int r1 = r0 + 1;
  bool has1 = r1 < M;
  float acc0[N_CLASS], acc1[N_CLASS];
#pragma unroll
  for (int n = 0; n < N_CLASS; n++) { acc0[n] = sb2[n]; acc1[n] = sb2[n]; }
  const unsigned short* h0 = H + (size_t)r0 * N_HID;
  const unsigned short* h1 = H + (size_t)(has1 ? r1 : r0) * N_HID;
  for (int k0 = 0; k0 < N_HID; k0 += 8) {
    u16x8 va = *(const u16x8*)(h0 + k0);
    u16x8 vb = *(const u16x8*)(h1 + k0);
#pragma unroll
    for (int j = 0; j < 8; j++) {
      float a0 = b2f(va[j]), a1 = b2f(vb[j]);
      const float* wrow = &Ws[(k0 + j) * N_CLASS];
#pragma unroll
      for (int n = 0; n < N_CLASS; n++) {
        float wv = wrow[n];
        acc0[n] = fmaf(a0, wv, acc0[n]);
        acc1[n] = fmaf(a1, wv, acc1[n]);
      }
    }
  }
  unsigned short* o0 = O + (size_t)r0 * N_CLASS;
#pragma unroll
  for (int n = 0; n < N_CLASS; n += 4) {
    ushort4 p;
    p.x = f2bu(acc0[n]); p.y = f2bu(acc0[n + 1]);
    p.z = f2bu(acc0[n + 2]); p.w = f2bu(acc0[n + 3]);
    *(ushort4*)(o0 + n) = p;
  }
  if (has1) {
    unsigned short* o1 = O + (size_t)r1 * N_CLASS;
#pragma unroll
    for (int n = 0; n < N_CLASS; n += 4) {
      ushort4 p;
      p.x = f2bu(acc1[n]); p.y = f2bu(acc1[n + 1]);
      p.z = f2bu(acc1[n + 2]); p.w = f2bu(acc1[n + 3]);
      *(ushort4*)(o1 + n) = p;
    }
  }
}

// ---------------------------------------------------------------------------
// SPMM2 (F=40, bf16 X, packed cvp) + fused log_softmax: wave/row, unroll 4
// ---------------------------------------------------------------------------
__global__ __launch_bounds__(256) void spmm_csr_40_lsm(
    const int* __restrict__ row_ptr, const unsigned int* __restrict__ cvp,
    const unsigned short* __restrict__ X, float* __restrict__ Out, int M) {
  int wave = (blockIdx.x * 256 + threadIdx.x) >> 6;
  int lane = threadIdx.x & 63;
  if (wave >= M) return;
  int start = row_ptr[wave], end = row_ptr[wave + 1];
  bool act = lane < N_CLASS;
  int ln = act ? lane : 0;
  const unsigned short* Xc = X + ln;
  float acc = 0.f;
  int e = start;
  for (; e + 4 <= end; e += 4) {
    unsigned int p0 = cvp[e], p1 = cvp[e + 1], p2 = cvp[e + 2], p3 = cvp[e + 3];
    unsigned short x0 = Xc[(size_t)(p0 >> 15) * N_CLASS];
    unsigned short x1 = Xc[(size_t)(p1 >> 15) * N_CLASS];
    unsigned short x2 = Xc[(size_t)(p2 >> 15) * N_CLASS];
    unsigned short x3 = Xc[(size_t)(p3 >> 15) * N_CLASS];
    acc = fmaf(decode_val(p0), b2f(x0), acc);
    acc = fmaf(decode_val(p1), b2f(x1), acc);
    acc = fmaf(decode_val(p2), b2f(x2), acc);
    acc = fmaf(decode_val(p3), b2f(x3), acc);
  }
  for (; e < end; e++) {
    unsigned int p0 = cvp[e];
    acc = fmaf(decode_val(p0), b2f(Xc[(size_t)(p0 >> 15) * N_CLASS]), acc);
  }
  float mv = act ? acc : -INFINITY;
#pragma unroll
  for (int off = 32; off; off >>= 1) mv = fmaxf(mv, __shfl_xor(mv, off));
  float ex = act ? expf(acc - mv) : 0.f;
  float s = ex;
#pragma unroll
  for (int off = 32; off; off >>= 1) s += __shfl_xor(s, off);
  float lse = mv + logf(s);
  if (act) Out[(size_t)wave * N_CLASS + lane] = acc - lse;
}

// ---------------------------------------------------------------------------
extern "C" void kernel_launch(void* const* d_in, const int* in_sizes, int n_in,
                              void* d_out, int out_size, void* d_ws, size_t ws_size,
                              hipStream_t stream) {
  const float* feat = (const float*)d_in[0];
  const int* er     = (const int*)d_in[1];
  const int* ec     = (const int*)d_in[2];
  const float* ev   = (const float*)d_in[3];
  const float* W1   = (const float*)d_in[4];
  const float* b1   = (const float*)d_in[5];
  const float* W2   = (const float*)d_in[6];
  const float* b2   = (const float*)d_in[7];
  float* out = (float*)d_out;
  const int M = N_NODES;
  const int E = in_sizes[1];

  char* ws = (char*)d_ws;
  unsigned char* h      = (unsigned char*)(ws);                  // 25.6 MB fp8
  unsigned short* hpost = (unsigned short*)(ws + 25600000);      // 51.2 MB bf16
  unsigned short* o     = (unsigned short*)(ws + 76800000);      // 8 MB bf16
  int* row_ptr          = (int*)(ws + 84800000);                 // 400,004 B
  int* cursor           = (int*)(ws + 85200016);                 // 400,000 B
  int* bsum             = (int*)(ws + 85600016);                 // 512 B
  unsigned int* cvp     = (unsigned int*)(ws + 85600528);        // 12.8 MB
  unsigned int* cvps    = (unsigned int*)(ws + 98400528);        // 12.8 MB
  unsigned short* W1Tsw = (unsigned short*)(ws + 111200528);     // 256 KB

  const int NB1 = (M + 1023) / 1024;  // 98
  const int SB = 2048;
  const int GB = (M + 31) / 32;       // 3125

  (void)hipMemsetAsync(cursor, 0, (size_t)M * sizeof(int), stream);
  prep_kernel<<<1024, 256, 0, stream>>>(W1, W1Tsw, er, ec, ev, cursor, cvps, E);
  scan1_kernel<<<NB1, 1024, 0, stream>>>(cursor, bsum, M);
  scan2_kernel<<<1, 64, 0, stream>>>(bsum, row_ptr, NB1, M);
  scan3_kernel<<<(M + 255) / 256, 256, 0, stream>>>(cursor, bsum, row_ptr, M);
  fused_sg<<<SB + GB, 256, 0, stream>>>(er, cvps, cursor, cvp, E,
                                        feat, W1Tsw, b1, h, M, SB);
  spmm_fp8<<<(M + 3) / 4, 256, 0, stream>>>(row_ptr, cvp, h, hpost, M);
  gemm2_kernel<<<(M + 511) / 512, 256, 0, stream>>>(hpost, W2, b2, o, M);
  spmm_csr_40_lsm<<<(M + 3) / 4, 256, 0, stream>>>(row_ptr, cvp, o, out, M);
}